// Round 14
// baseline (241.468 us; speedup 1.0000x reference)
//
#include <hip/hip_runtime.h>
#include <math.h>

#define B_   16
#define S_   1056
#define DM_  256
#define H_   8
#define DK_  32
#define TXT_ 32
#define VID_ 1024
#define SS_  (S_*S_)          // 1115136
#define NQT_ 66               // q-tiles of 16 rows
#define NKT_ 66               // k-tiles of 16
#define MASK_BLKS 1089        // (66*66*64)/256

#define LOG2_10000f 13.28771237954945f
#define LOG2_GAMMAf (-0.15200309344504995f)   // log2(0.9)
#define RSQRT_DKf   0.17677669529663687f      // 1/sqrt(32)
#define TWO_PIf     6.283185307179586f
#define LOG2Ef      1.4426950408889634f

typedef __attribute__((ext_vector_type(8))) short bf16x8;
typedef __attribute__((ext_vector_type(4))) short bf16x4;
typedef __attribute__((ext_vector_type(4))) float f32x4;

__device__ __forceinline__ short f2bf(float f){
    unsigned u = __float_as_uint(f);
    unsigned r = u + 0x7FFFu + ((u >> 16) & 1u);   // RNE
    return (short)(r >> 16);
}
__device__ __forceinline__ float bf2f(unsigned short s){
    return __uint_as_float(((unsigned)s) << 16);
}
__device__ __forceinline__ float fexp2(float x){
#if __has_builtin(__builtin_amdgcn_exp2f)
    return __builtin_amdgcn_exp2f(x);
#else
    return exp2f(x);
#endif
}
// pack 4 f32 -> bf16x4 via v_cvt_pk_bf16_f32 (2 instr instead of ~16)
__device__ __forceinline__ bf16x4 pack_bf16x4(float e0, float e1, float e2, float e3){
    unsigned w0, w1;
    asm("v_cvt_pk_bf16_f32 %0, %1, %2" : "=v"(w0) : "v"(e0), "v"(e1));
    asm("v_cvt_pk_bf16_f32 %0, %1, %2" : "=v"(w1) : "v"(e2), "v"(e3));
    uint2 u = make_uint2(w0, w1);
    return *(bf16x4*)&u;
}

// K=16 bf16 MFMA: A-frag lane l holds A[row=l%16][k=4(l/16)+j] — exactly the
// D-layout of the QK^T tile, so P feeds PV in-lane.
__device__ __forceinline__ f32x4 mfma16(bf16x4 a, bf16x4 b, f32x4 c){
#if __has_builtin(__builtin_amdgcn_mfma_f32_16x16x16bf16_1k)
    return __builtin_amdgcn_mfma_f32_16x16x16bf16_1k(a, b, c, 0, 0, 0);
#else
    f32x4 d = c;
    asm("v_mfma_f32_16x16x16_bf16 %0, %1, %2, %0" : "+v"(d) : "v"(a), "v"(b));
    return d;
#endif
}

// ---------------- mask: fragment-order maskf (pre-scaled by log2e) + loss partials ----------------
// Thread T -> (qt,kt,l): 4 mask elems (q = qt*16 + l%16, k = kt*16 + 4*(l/16)+j).
__global__ __launch_bounds__(256) void k_mask(const float* __restrict__ lvr,
                       const int* __restrict__ row_idx, const int* __restrict__ col_idx,
                       short* __restrict__ maskf, float* __restrict__ partials)
{
    int T  = blockIdx.x*256 + threadIdx.x;
    int l  = T & 63;
    int qk = T >> 6;                  // qt*66 + kt
    int qt = qk / 66;
    int kt = qk - qt*66;
    int i  = qt*16 + (l & 15);
    int j0 = kt*16 + 4*(l >> 4);
    size_t idx = (size_t)i*S_ + j0;
    int4 ri4 = *(const int4*)&row_idx[idx];
    int4 ci4 = *(const int4*)&col_idx[idx];
    int rr[4] = {ri4.x, ri4.y, ri4.z, ri4.w};
    int cc[4] = {ci4.x, ci4.y, ci4.z, ci4.w};
    float vrs = 0.f;
    short4 mq;
    short* mp = (short*)&mq;
    #pragma unroll
    for (int jj = 0; jj < 4; ++jj) {
        int j = j0 + jj;
        float vr, lm;
        if (i == j) { vr = 0.f; lm = 1.f; }
        else {
            float t = lvr[(size_t)rr[jj]*VID_ + cc[jj]];
            float sg = 1.f/(1.f + expf(-t));
            vr = sg; lm = sg;
        }
        float dmat = (i >= j) ? exp2f((float)(i-j)*LOG2_GAMMAf) : 0.f;
        mp[jj] = f2bf(dmat * lm * LOG2Ef);   // pre-scaled: exp(s*m) = exp2(s*m')
        vrs += vr;
    }
    *(short4*)&maskf[(size_t)qk*256 + l*4] = mq;

    float s = vrs;
    #pragma unroll
    for (int m=1; m<64; m<<=1) s += __shfl_xor(s, m, 64);
    __shared__ float ws4[4];
    if ((threadIdx.x & 63) == 0) ws4[threadIdx.x>>6] = s;
    __syncthreads();
    if (threadIdx.x == 0) partials[blockIdx.x] = ws4[0]+ws4[1]+ws4[2]+ws4[3];
}

__global__ __launch_bounds__(256) void k_loss(const float* __restrict__ partials,
                                              float* __restrict__ out_loss)
{
    float s = 0.f;
    for (int i = threadIdx.x; i < MASK_BLKS; i += 256) s += partials[i];
    #pragma unroll
    for (int m=1; m<64; m<<=1) s += __shfl_xor(s, m, 64);
    __shared__ float ws4[4];
    if ((threadIdx.x & 63) == 0) ws4[threadIdx.x>>6] = s;
    __syncthreads();
    if (threadIdx.x == 0) out_loss[0] = (ws4[0]+ws4[1]+ws4[2]+ws4[3]) * (1.f/(float)SS_);
}

// ---------------- weight prep ----------------
__global__ __launch_bounds__(256) void k_wprep(
    const float* __restrict__ Wtq, const float* __restrict__ Wtk, const float* __restrict__ Wtv,
    const float* __restrict__ Wvq, const float* __restrict__ Wvk, const float* __restrict__ Wvv,
    const float* __restrict__ Wout, short* __restrict__ WTall, short* __restrict__ WoB)
{
    int seg = blockIdx.x >> 8;
    int r   = blockIdx.x & 255;
    int tid = threadIdx.x;
    if (seg == 6) {
        WoB[r*256 + tid] = f2bf(Wout[r*256 + tid]);
    } else {
        const float* Wsrc = seg==0?Wtq: seg==1?Wtk: seg==2?Wtv: seg==3?Wvq: seg==4?Wvk: Wvv;
        WTall[(size_t)seg*65536 + r*256 + tid] = f2bf(Wsrc[tid*256 + r]);
    }
}

// ---------------- QKV projection via MFMA -> Qb row-major, Kf/Vf fragment-tiled ----------------
__global__ __launch_bounds__(256, 2) void k_qkv(const float* __restrict__ src,
    const short* __restrict__ WTq, const short* __restrict__ WTk, const short* __restrict__ WTv,
    short* __restrict__ Qb, short* __restrict__ Kf, short* __restrict__ Vf, int is_txt)
{
    __shared__ __align__(16) short xb[3][16][256];   // 24 KB
    __shared__ float invf[128];
    __shared__ float lbs[128];
    int tid = threadIdx.x;
    int r0 = blockIdx.x * 16;
    int b, srow0;
    if (is_txt) { b = r0 >> 5;  srow0 = r0 & 31; }
    else        { b = r0 >> 10; srow0 = TXT_ + (r0 & 1023); }
    int t16 = srow0 >> 4;

    if (tid < 128) {
        float fk = (float)tid;
        invf[tid] = exp2f(-fk*(1.f/128.f)*LOG2_10000f);
        lbs[tid]  = log2f((2.f*fk + 102.4f) * (1.f/358.4f));
    }
    __syncthreads();

    #pragma unroll
    for (int it = 0; it < 8; ++it) {
        int task = it*256 + tid;
        int k  = task >> 4;
        int rr = task & 15;
        int srow = srow0 + rr;
        float2 x01 = ((const float2*)(src + ((size_t)b*S_ + srow)*DM_))[k];
        float a0, a1, c0, c1;
        if (is_txt) {
            float xe  = (float)(srow + 1) * (TWO_PIf/(32.f + 1e-6f));
            float arg = xe * invf[k];
            float sn = __sinf(arg), cs = __cosf(arg);
            a0 = x01.x + sn; a1 = x01.y + cs;
            c0 = a0; c1 = a1;
        } else {
            int l = srow - TXT_;
            float arg = (float)l * invf[k];
            float sn = __sinf(arg), cs = __cosf(arg);
            float scale = exp2f((float)l*(1.f/512.f)*lbs[k]);
            float rsc = 1.f/scale;
            float y0 = x01.x*cs - x01.y*sn;
            float y1 = x01.y*cs + x01.x*sn;
            a0 = y0*scale; a1 = y1*scale;
            c0 = y0*rsc;   c1 = y1*rsc;
        }
        int col = (2*k) ^ ((rr&7)<<3);
        *(short2*)&xb[0][rr][col] = make_short2(f2bf(a0), f2bf(a1));
        *(short2*)&xb[1][rr][col] = make_short2(f2bf(c0), f2bf(c1));
        *(short2*)&xb[2][rr][col] = make_short2(f2bf(x01.x), f2bf(x01.y));
    }
    __syncthreads();

    int lane = tid & 63;
    int w    = tid >> 6;
    int lr   = lane & 15;
    int lg   = lane >> 4;
    int swzl = (lr & 7) << 3;

    const short* WTs[3] = {WTq, WTk, WTv};
    #pragma unroll
    for (int m = 0; m < 3; ++m) {
        bf16x8 xf[8];
        #pragma unroll
        for (int kk = 0; kk < 8; ++kk)
            xf[kk] = *(const bf16x8*)&xb[m][lr][(kk*32 + lg*8) ^ swzl];
        #pragma unroll
        for (int ct = 0; ct < 4; ++ct) {
            int tb = (w + ct*4) * 16;
            const short* Wp = WTs[m] + (size_t)(tb+lr)*DM_ + lg*8;
            f32x4 acc = {0.f,0.f,0.f,0.f};
            if (m < 2) {
                #pragma unroll
                for (int kk = 0; kk < 8; ++kk) {
                    bf16x8 wf = *(const bf16x8*)(Wp + kk*32);
                    acc = __builtin_amdgcn_mfma_f32_16x16x32_bf16(wf, xf[kk], acc, 0, 0, 0);
                }
                int h  = tb >> 5;
                int d0 = (tb & 31) + lg*4;
                short4 s4;
                if (m == 0) {
                    s4.x=f2bf(acc[0]*RSQRT_DKf); s4.y=f2bf(acc[1]*RSQRT_DKf);
                    s4.z=f2bf(acc[2]*RSQRT_DKf); s4.w=f2bf(acc[3]*RSQRT_DKf);
                    size_t off = ((size_t)(b*H_+h)*S_ + srow0+lr)*DK_ + d0;
                    *(short4*)&Qb[off] = s4;
                } else {
                    s4.x=f2bf(acc[0]); s4.y=f2bf(acc[1]);
                    s4.z=f2bf(acc[2]); s4.w=f2bf(acc[3]);
                    int lK = lr + 16*(d0 >> 3);
                    *(short4*)&Kf[((((size_t)(b*H_+h)*NKT_ + t16) << 9)) + lK*8 + (d0 & 7)] = s4;
                }
            } else {
                #pragma unroll
                for (int kk = 0; kk < 8; ++kk) {
                    bf16x8 wf = *(const bf16x8*)(Wp + kk*32);
                    acc = __builtin_amdgcn_mfma_f32_16x16x32_bf16(xf[kk], wf, acc, 0, 0, 0);
                }
                int o = tb + lr;
                int h = o >> 5;
                int dh = (tb >> 4) & 1;
                short4 s4;
                s4.x=f2bf(acc[0]); s4.y=f2bf(acc[1]);
                s4.z=f2bf(acc[2]); s4.w=f2bf(acc[3]);
                *(short4*)&Vf[((((size_t)(b*H_+h)*NKT_ + t16)*2 + dh) << 8) + lane*4] = s4;
            }
        }
    }
}

// ---------------- kernel A: denominators + ctx — 256-thr blocks, wave = 1 head ----------------
#define CTX_TILE(KF, MV, VA, VB, PV0, PV1)                                        \
    {                                                                             \
        f32x4 acc = {0.f,0.f,0.f,0.f};                                            \
        acc = __builtin_amdgcn_mfma_f32_16x16x32_bf16(KF, qfrag, acc, 0, 0, 0);   \
        float e0 = fexp2(acc[0]*bf2f(MV.x));                                      \
        float e1 = fexp2(acc[1]*bf2f(MV.y));                                      \
        float e2 = fexp2(acc[2]*bf2f(MV.z));                                      \
        float e3 = fexp2(acc[3]*bf2f(MV.w));                                      \
        rssum += (e0+e1) + (e2+e3);                                               \
        bf16x4 pb = pack_bf16x4(e0, e1, e2, e3);                                  \
        PV0 = mfma16(pb, VA, PV0);                                                \
        PV1 = mfma16(pb, VB, PV1);                                                \
    }

__global__ __launch_bounds__(256, 6) void k_ctx(const short* __restrict__ Qb,
    const short* __restrict__ Kf, const short* __restrict__ Vf,
    const short* __restrict__ maskf, short* __restrict__ ctxb, float* __restrict__ denomG)
{
    int tid  = threadIdx.x;
    int lane = tid & 63;
    int w    = tid >> 6;          // wave 0..3
    int b    = blockIdx.x & 15;   // b-inner: XCD pinning (b%8)
    int qq   = blockIdx.x >> 4;   // 0..131
    int qt   = qq >> 1;
    int hh   = qq & 1;
    int head = hh*4 + w;
    int q0   = qt * 16;
    int lr   = lane & 15;
    int lg   = lane >> 4;

    const int bh = b*H_ + head;
    bf16x8 qfrag = *(const bf16x8*)(Qb + ((size_t)bh*S_ + q0 + lr)*DK_ + lg*8);
    const short* Kp = Kf + (((size_t)bh*NKT_) << 9) + lane*8;    // + t*512
    const short* Vp = Vf + (((size_t)bh*NKT_) << 9) + lane*4;    // + (t*2+dh)*256
    const short* Mp = maskf + (((size_t)qt*NKT_) << 8) + lane*4; // + t*256

    float rssum = 0.f;
    f32x4 pvA0 = {0.f,0.f,0.f,0.f}, pvA1 = {0.f,0.f,0.f,0.f};
    f32x4 pvB0 = {0.f,0.f,0.f,0.f}, pvB1 = {0.f,0.f,0.f,0.f};

    for (int g = 0; g < 11; ++g) {
        int tb = g * 6;
        bf16x8 K[6]; ushort4 M[6]; short4 V[12];
        #pragma unroll
        for (int c = 0; c < 6; ++c) {
            int t = tb + c;
            K[c] = *(const bf16x8*)(Kp + (unsigned)t*512);
            M[c] = *(const ushort4*)(Mp + (unsigned)t*256);
            V[2*c]   = *(const short4*)(Vp + (unsigned)(t*2  )*256);
            V[2*c+1] = *(const short4*)(Vp + (unsigned)(t*2+1)*256);
        }
        #pragma unroll
        for (int c = 0; c < 3; ++c) {
            CTX_TILE(K[2*c],   M[2*c],   *(const bf16x4*)&V[4*c+0], *(const bf16x4*)&V[4*c+1], pvA0, pvA1)
            CTX_TILE(K[2*c+1], M[2*c+1], *(const bf16x4*)&V[4*c+2], *(const bf16x4*)&V[4*c+3], pvB0, pvB1)
        }
    }

    f32x4 pv0, pv1;
    pv0[0]=pvA0[0]+pvB0[0]; pv0[1]=pvA0[1]+pvB0[1]; pv0[2]=pvA0[2]+pvB0[2]; pv0[3]=pvA0[3]+pvB0[3];
    pv1[0]=pvA1[0]+pvB1[0]; pv1[1]=pvA1[1]+pvB1[1]; pv1[2]=pvA1[2]+pvB1[2]; pv1[3]=pvA1[3]+pvB1[3];

    rssum += __shfl_xor(rssum, 16, 64);
    rssum += __shfl_xor(rssum, 32, 64);
    float rd = 1.f / rssum;
    if (lane < 16)
        denomG[(size_t)bh*S_ + q0 + lane] = rd;

    #pragma unroll
    for (int r = 0; r < 4; ++r) {
        float rdq = __shfl(rd, 4*lg + r, 64);
        size_t off = ((size_t)b*S_ + q0 + 4*lg + r)*DM_ + head*DK_ + lr;
        ctxb[off]      = f2bf(pv0[r] * rdq);
        ctxb[off + 16] = f2bf(pv1[r] * rdq);
    }
}

// ---------------- kernel B: att by score recompute — maskf-aligned orientation ----------------
// mfma(A=kf, B=qf): lane l -> (q = q0 + l%16, k = k0 + 4*(l/16)+r) — matches maskf
// fragment exactly; att store = one float4 (4 consecutive k) per lane.
__global__ __launch_bounds__(256, 4) void k_att(const short* __restrict__ Qb,
    const short* __restrict__ Kf, const short* __restrict__ maskf,
    const float* __restrict__ denomG, float* __restrict__ att)
{
    int tid  = threadIdx.x;
    int lane = tid & 63;
    int w    = tid >> 6;
    int b    = blockIdx.x & 15;       // b-inner: XCD pinning
    int qt   = blockIdx.x >> 4;
    int q0   = qt * 16;
    int lr   = lane & 15;
    int lg   = lane >> 4;

    // per-lane denominators for q = q0+lr, all 8 heads (registers, no LDS)
    float rdv[8];
    #pragma unroll
    for (int h = 0; h < 8; ++h)
        rdv[h] = denomG[(size_t)(b*H_+h)*S_ + q0 + lr] * 0.125f;

    bf16x8 qf[8];
    #pragma unroll
    for (int h = 0; h < 8; ++h)
        qf[h] = *(const bf16x8*)(Qb + ((size_t)(b*H_+h)*S_ + q0+lr)*DK_ + lg*8);

    int nt = (w < 2) ? 17 : 16;
    for (int t = 0; t < nt; ++t) {
        int kt = t*4 + w;
        int k0 = kt*16;
        bf16x8 kf[8];
        #pragma unroll
        for (int h = 0; h < 8; ++h)
            kf[h] = *(const bf16x8*)(Kf + (((size_t)(b*H_+h)*NKT_ + kt) << 9) + lane*8);
        ushort4 mq = *(const ushort4*)(maskf + (((size_t)qt*NKT_ + kt) << 8) + lane*4);
        float m0 = bf2f(mq.x), m1 = bf2f(mq.y), m2 = bf2f(mq.z), m3 = bf2f(mq.w);
        f32x4 a = {0.f,0.f,0.f,0.f};
        #pragma unroll
        for (int h = 0; h < 8; ++h) {
            f32x4 s = {0.f,0.f,0.f,0.f};
            s = __builtin_amdgcn_mfma_f32_16x16x32_bf16(kf[h], qf[h], s, 0, 0, 0);
            a[0] = fmaf(fexp2(s[0]*m0), rdv[h], a[0]);
            a[1] = fmaf(fexp2(s[1]*m1), rdv[h], a[1]);
            a[2] = fmaf(fexp2(s[2]*m2), rdv[h], a[2]);
            a[3] = fmaf(fexp2(s[3]*m3), rdv[h], a[3]);
        }
        float4 o4 = make_float4(a[0], a[1], a[2], a[3]);
        *(float4*)&att[((size_t)b*S_ + q0+lr)*S_ + k0 + 4*lg] = o4;
    }
}

// ---------------- out projection via MFMA (no LDS) ----------------
__global__ __launch_bounds__(256, 2) void k_outproj(const short* __restrict__ ctxb,
    const short* __restrict__ WoB, const float* __restrict__ bias, float* __restrict__ out)
{
    int tid  = threadIdx.x;
    int lane = tid & 63;
    int w    = tid >> 6;
    int lr   = lane & 15;
    int lg   = lane >> 4;
    int r0   = blockIdx.x * 16;

    bf16x8 cf[8];
    #pragma unroll
    for (int kk = 0; kk < 8; ++kk)
        cf[kk] = *(const bf16x8*)(ctxb + (size_t)(r0+lr)*DM_ + kk*32 + lg*8);

    #pragma unroll
    for (int ct = 0; ct < 4; ++ct) {
        int tb = (w + ct*4) * 16;
        const short* Wp = WoB + (size_t)(tb+lr)*DM_ + lg*8;
        f32x4 acc = {0.f,0.f,0.f,0.f};
        #pragma unroll
        for (int kk = 0; kk < 8; ++kk) {
            bf16x8 wf = *(const bf16x8*)(Wp + kk*32);
            acc = __builtin_amdgcn_mfma_f32_16x16x32_bf16(wf, cf[kk], acc, 0, 0, 0);
        }
        float4 b4 = *(const float4*)&bias[tb + lg*4];
        float4 o4 = make_float4(acc[0]+b4.x, acc[1]+b4.y, acc[2]+b4.z, acc[3]+b4.w);
        *(float4*)&out[(size_t)(r0+lr)*DM_ + tb + lg*4] = o4;
    }
}

extern "C" void kernel_launch(void* const* d_in, const int* in_sizes, int n_in,
                              void* d_out, int out_size, void* d_ws, size_t ws_size,
                              hipStream_t stream)
{
    (void)in_sizes; (void)n_in; (void)out_size; (void)ws_size;
    const float* src  = (const float*)d_in[0];
    const float* Wtq  = (const float*)d_in[1];
    const float* Wtk  = (const float*)d_in[2];
    const float* Wtv  = (const float*)d_in[3];
    const float* Wvq  = (const float*)d_in[4];
    const float* Wvk  = (const float*)d_in[5];
    const float* Wvv  = (const float*)d_in[6];
    const float* lvr  = (const float*)d_in[7];
    const float* Wout = (const float*)d_in[8];
    const float* bout = (const float*)d_in[9];
    const int*   rid  = (const int*)d_in[10];
    const int*   cid  = (const int*)d_in[11];

    const size_t QKV_SH = (size_t)B_*H_*S_*DK_;      // Qb shorts
    const size_t KF_SH  = (size_t)B_*H_*NKT_*512;    // Kf shorts
    const size_t VF_SH  = (size_t)B_*H_*NKT_*512;    // Vf shorts
    const size_t CTX_SH = (size_t)B_*S_*DM_;

    float* ws       = (float*)d_ws;
    float* partials = ws;                             // MASK_BLKS
    float* denomG   = partials + MASK_BLKS;           // B*H*S
    short* maskf    = (short*)(denomG + (size_t)B_*H_*S_);
    short* Qb       = maskf + SS_;
    short* Kf       = Qb + QKV_SH;
    short* Vf       = Kf + KF_SH;
    short* ctxb     = Vf + VF_SH;
    short* WTall    = ctxb + CTX_SH;                  // 6*65536
    short* WoB      = WTall + 6*65536;

    float* out  = (float*)d_out;
    float* att  = out + (size_t)B_*S_*DM_;
    float* loss = att + (size_t)B_*S_*S_;

    k_mask<<<MASK_BLKS, 256, 0, stream>>>(lvr, rid, cid, maskf, partials);
    k_wprep<<<7*256, 256, 0, stream>>>(Wtq, Wtk, Wtv, Wvq, Wvk, Wvv, Wout, WTall, WoB);
    k_qkv<<<(B_*TXT_)/16, 256, 0, stream>>>(src, WTall, WTall+65536, WTall+2*65536,
                                            Qb, Kf, Vf, 1);
    k_qkv<<<(B_*VID_)/16, 256, 0, stream>>>(src, WTall+3*65536, WTall+4*65536, WTall+5*65536,
                                            Qb, Kf, Vf, 0);
    k_ctx<<<B_*NQT_*2, 256, 0, stream>>>(Qb, Kf, Vf, maskf, ctxb, denomG);
    k_att<<<B_*NQT_, 256, 0, stream>>>(Qb, Kf, maskf, denomG, att);
    k_outproj<<<(B_*S_)/16, 256, 0, stream>>>(ctxb, WoB, bout, out);
    k_loss<<<1, 256, 0, stream>>>(partials, loss);
}

// Round 15
// 213.422 us; speedup vs baseline: 1.1314x; 1.1314x over previous
//
#include <hip/hip_runtime.h>
#include <math.h>

#define B_   16
#define S_   1056
#define DM_  256
#define H_   8
#define DK_  32
#define TXT_ 32
#define VID_ 1024
#define SS_  (S_*S_)          // 1115136
#define NQT_ 66               // q-tiles of 16 rows
#define NKT_ 66               // k-tiles of 16
#define MASK_BLKS 1089        // (66*66*64)/256

#define LOG2_10000f 13.28771237954945f
#define LOG2_GAMMAf (-0.15200309344504995f)   // log2(0.9)
#define RSQRT_DKf   0.17677669529663687f      // 1/sqrt(32)
#define TWO_PIf     6.283185307179586f
#define LOG2Ef      1.4426950408889634f

typedef __attribute__((ext_vector_type(8))) short bf16x8;
typedef __attribute__((ext_vector_type(4))) short bf16x4;
typedef __attribute__((ext_vector_type(4))) float f32x4;

__device__ __forceinline__ short f2bf(float f){
    unsigned u = __float_as_uint(f);
    unsigned r = u + 0x7FFFu + ((u >> 16) & 1u);   // RNE
    return (short)(r >> 16);
}
__device__ __forceinline__ float bf2f(unsigned short s){
    return __uint_as_float(((unsigned)s) << 16);
}
__device__ __forceinline__ float fexp2(float x){
#if __has_builtin(__builtin_amdgcn_exp2f)
    return __builtin_amdgcn_exp2f(x);
#else
    return exp2f(x);
#endif
}
__device__ __forceinline__ bf16x4 pack_bf16x4(float e0, float e1, float e2, float e3){
    unsigned w0, w1;
    asm("v_cvt_pk_bf16_f32 %0, %1, %2" : "=v"(w0) : "v"(e0), "v"(e1));
    asm("v_cvt_pk_bf16_f32 %0, %1, %2" : "=v"(w1) : "v"(e2), "v"(e3));
    uint2 u = make_uint2(w0, w1);
    return *(bf16x4*)&u;
}

// K=16 bf16 MFMA: A-frag lane l holds A[row=l%16][k=4(l/16)+j] — matches the
// QK^T D-fragment, so P feeds PV in-lane.
__device__ __forceinline__ f32x4 mfma16(bf16x4 a, bf16x4 b, f32x4 c){
#if __has_builtin(__builtin_amdgcn_mfma_f32_16x16x16bf16_1k)
    return __builtin_amdgcn_mfma_f32_16x16x16bf16_1k(a, b, c, 0, 0, 0);
#else
    f32x4 d = c;
    asm("v_mfma_f32_16x16x16_bf16 %0, %1, %2, %0" : "+v"(d) : "v"(a), "v"(b));
    return d;
#endif
}

// ---------------- mask: fragment-order maskf (pre-scaled by log2e) + loss partials ----------------
__global__ __launch_bounds__(256) void k_mask(const float* __restrict__ lvr,
                       const int* __restrict__ row_idx, const int* __restrict__ col_idx,
                       short* __restrict__ maskf, float* __restrict__ partials)
{
    int T  = blockIdx.x*256 + threadIdx.x;
    int l  = T & 63;
    int qk = T >> 6;                  // qt*66 + kt
    int qt = qk / 66;
    int kt = qk - qt*66;
    int i  = qt*16 + (l & 15);
    int j0 = kt*16 + 4*(l >> 4);
    size_t idx = (size_t)i*S_ + j0;
    int4 ri4 = *(const int4*)&row_idx[idx];
    int4 ci4 = *(const int4*)&col_idx[idx];
    int rr[4] = {ri4.x, ri4.y, ri4.z, ri4.w};
    int cc[4] = {ci4.x, ci4.y, ci4.z, ci4.w};
    float vrs = 0.f;
    short4 mq;
    short* mp = (short*)&mq;
    #pragma unroll
    for (int jj = 0; jj < 4; ++jj) {
        int j = j0 + jj;
        float vr, lm;
        if (i == j) { vr = 0.f; lm = 1.f; }
        else {
            float t = lvr[(size_t)rr[jj]*VID_ + cc[jj]];
            float sg = 1.f/(1.f + expf(-t));
            vr = sg; lm = sg;
        }
        float dmat = (i >= j) ? exp2f((float)(i-j)*LOG2_GAMMAf) : 0.f;
        mp[jj] = f2bf(dmat * lm * LOG2Ef);   // exp(s*m) = exp2(s*m')
        vrs += vr;
    }
    *(short4*)&maskf[(size_t)qk*256 + l*4] = mq;

    float s = vrs;
    #pragma unroll
    for (int m=1; m<64; m<<=1) s += __shfl_xor(s, m, 64);
    __shared__ float ws4[4];
    if ((threadIdx.x & 63) == 0) ws4[threadIdx.x>>6] = s;
    __syncthreads();
    if (threadIdx.x == 0) partials[blockIdx.x] = ws4[0]+ws4[1]+ws4[2]+ws4[3];
}

__global__ __launch_bounds__(256) void k_loss(const float* __restrict__ partials,
                                              float* __restrict__ out_loss)
{
    float s = 0.f;
    for (int i = threadIdx.x; i < MASK_BLKS; i += 256) s += partials[i];
    #pragma unroll
    for (int m=1; m<64; m<<=1) s += __shfl_xor(s, m, 64);
    __shared__ float ws4[4];
    if ((threadIdx.x & 63) == 0) ws4[threadIdx.x>>6] = s;
    __syncthreads();
    if (threadIdx.x == 0) out_loss[0] = (ws4[0]+ws4[1]+ws4[2]+ws4[3]) * (1.f/(float)SS_);
}

// ---------------- weight prep ----------------
__global__ __launch_bounds__(256) void k_wprep(
    const float* __restrict__ Wtq, const float* __restrict__ Wtk, const float* __restrict__ Wtv,
    const float* __restrict__ Wvq, const float* __restrict__ Wvk, const float* __restrict__ Wvv,
    const float* __restrict__ Wout, short* __restrict__ WTall, short* __restrict__ WoB)
{
    int seg = blockIdx.x >> 8;
    int r   = blockIdx.x & 255;
    int tid = threadIdx.x;
    if (seg == 6) {
        WoB[r*256 + tid] = f2bf(Wout[r*256 + tid]);
    } else {
        const float* Wsrc = seg==0?Wtq: seg==1?Wtk: seg==2?Wtv: seg==3?Wvq: seg==4?Wvk: Wvv;
        WTall[(size_t)seg*65536 + r*256 + tid] = f2bf(Wsrc[tid*256 + r]);
    }
}

// ---------------- QKV projection via MFMA -> Qb row-major, Kf/Vf fragment-tiled ----------------
// Kf tile: 1KB, lane l holds K[k=t*16+l%16][dk=8*(l/16)..+7] at l*16B.
// Vf tile: 1KB, lane l holds V[k=t*16+4*(l/16)+j][d=l%16] at l*16B (shorts 0-3)
//          and V[...][d=16+l%16] at l*16B+8 (shorts 4-7) — both d-halves one dwordx4.
__global__ __launch_bounds__(256, 2) void k_qkv(const float* __restrict__ src,
    const short* __restrict__ WTq, const short* __restrict__ WTk, const short* __restrict__ WTv,
    short* __restrict__ Qb, short* __restrict__ Kf, short* __restrict__ Vf, int is_txt)
{
    __shared__ __align__(16) short xb[3][16][256];   // 24 KB
    __shared__ float invf[128];
    __shared__ float lbs[128];
    int tid = threadIdx.x;
    int r0 = blockIdx.x * 16;
    int b, srow0;
    if (is_txt) { b = r0 >> 5;  srow0 = r0 & 31; }
    else        { b = r0 >> 10; srow0 = TXT_ + (r0 & 1023); }
    int t16 = srow0 >> 4;

    if (tid < 128) {
        float fk = (float)tid;
        invf[tid] = exp2f(-fk*(1.f/128.f)*LOG2_10000f);
        lbs[tid]  = log2f((2.f*fk + 102.4f) * (1.f/358.4f));
    }
    __syncthreads();

    #pragma unroll
    for (int it = 0; it < 8; ++it) {
        int task = it*256 + tid;
        int k  = task >> 4;
        int rr = task & 15;
        int srow = srow0 + rr;
        float2 x01 = ((const float2*)(src + ((size_t)b*S_ + srow)*DM_))[k];
        float a0, a1, c0, c1;
        if (is_txt) {
            float xe  = (float)(srow + 1) * (TWO_PIf/(32.f + 1e-6f));
            float arg = xe * invf[k];
            float sn = __sinf(arg), cs = __cosf(arg);
            a0 = x01.x + sn; a1 = x01.y + cs;
            c0 = a0; c1 = a1;
        } else {
            int l = srow - TXT_;
            float arg = (float)l * invf[k];
            float sn = __sinf(arg), cs = __cosf(arg);
            float scale = exp2f((float)l*(1.f/512.f)*lbs[k]);
            float rsc = 1.f/scale;
            float y0 = x01.x*cs - x01.y*sn;
            float y1 = x01.y*cs + x01.x*sn;
            a0 = y0*scale; a1 = y1*scale;
            c0 = y0*rsc;   c1 = y1*rsc;
        }
        int col = (2*k) ^ ((rr&7)<<3);
        *(short2*)&xb[0][rr][col] = make_short2(f2bf(a0), f2bf(a1));
        *(short2*)&xb[1][rr][col] = make_short2(f2bf(c0), f2bf(c1));
        *(short2*)&xb[2][rr][col] = make_short2(f2bf(x01.x), f2bf(x01.y));
    }
    __syncthreads();

    int lane = tid & 63;
    int w    = tid >> 6;
    int lr   = lane & 15;
    int lg   = lane >> 4;
    int swzl = (lr & 7) << 3;

    const short* WTs[3] = {WTq, WTk, WTv};
    #pragma unroll
    for (int m = 0; m < 3; ++m) {
        bf16x8 xf[8];
        #pragma unroll
        for (int kk = 0; kk < 8; ++kk)
            xf[kk] = *(const bf16x8*)&xb[m][lr][(kk*32 + lg*8) ^ swzl];
        #pragma unroll
        for (int ct = 0; ct < 4; ++ct) {
            int tb = (w + ct*4) * 16;
            const short* Wp = WTs[m] + (size_t)(tb+lr)*DM_ + lg*8;
            f32x4 acc = {0.f,0.f,0.f,0.f};
            if (m < 2) {
                #pragma unroll
                for (int kk = 0; kk < 8; ++kk) {
                    bf16x8 wf = *(const bf16x8*)(Wp + kk*32);
                    acc = __builtin_amdgcn_mfma_f32_16x16x32_bf16(wf, xf[kk], acc, 0, 0, 0);
                }
                int h  = tb >> 5;
                int d0 = (tb & 31) + lg*4;
                short4 s4;
                if (m == 0) {
                    s4.x=f2bf(acc[0]*RSQRT_DKf); s4.y=f2bf(acc[1]*RSQRT_DKf);
                    s4.z=f2bf(acc[2]*RSQRT_DKf); s4.w=f2bf(acc[3]*RSQRT_DKf);
                    size_t off = ((size_t)(b*H_+h)*S_ + srow0+lr)*DK_ + d0;
                    *(short4*)&Qb[off] = s4;
                } else {
                    s4.x=f2bf(acc[0]); s4.y=f2bf(acc[1]);
                    s4.z=f2bf(acc[2]); s4.w=f2bf(acc[3]);
                    int lK = lr + 16*(d0 >> 3);
                    *(short4*)&Kf[((((size_t)(b*H_+h)*NKT_ + t16) << 9)) + lK*8 + (d0 & 7)] = s4;
                }
            } else {
                #pragma unroll
                for (int kk = 0; kk < 8; ++kk) {
                    bf16x8 wf = *(const bf16x8*)(Wp + kk*32);
                    acc = __builtin_amdgcn_mfma_f32_16x16x32_bf16(xf[kk], wf, acc, 0, 0, 0);
                }
                int o = tb + lr;
                int h = o >> 5;
                int dh = (tb >> 4) & 1;
                short4 s4;
                s4.x=f2bf(acc[0]); s4.y=f2bf(acc[1]);
                s4.z=f2bf(acc[2]); s4.w=f2bf(acc[3]);
                // interleaved: both d-halves of a tile in one 16B lane slot
                *(short4*)&Vf[((((size_t)(b*H_+h)*NKT_ + t16)) << 9) + lane*8 + dh*4] = s4;
            }
        }
    }
}

// ---------------- kernel A: denominators + ctx — 32 q-rows/wave, merged V load ----------------
// Per 16-k tile: 1 K load + 1 V load + 2 M loads -> 2 MFMA32 + 8 exp + 4 mfma16.
// K/V read once per 32 q (was per 16): L2 traffic 1.4 -> 0.85 GB.
#define CTX_TILE2(KF, M0V, M1V, VV)                                               \
    {                                                                             \
        f32x4 acc0 = {0.f,0.f,0.f,0.f};                                           \
        acc0 = __builtin_amdgcn_mfma_f32_16x16x32_bf16(KF, qf0, acc0, 0, 0, 0);   \
        f32x4 acc1 = {0.f,0.f,0.f,0.f};                                           \
        acc1 = __builtin_amdgcn_mfma_f32_16x16x32_bf16(KF, qf1, acc1, 0, 0, 0);   \
        float e0 = fexp2(acc0[0]*bf2f(M0V.x));                                    \
        float e1 = fexp2(acc0[1]*bf2f(M0V.y));                                    \
        float e2 = fexp2(acc0[2]*bf2f(M0V.z));                                    \
        float e3 = fexp2(acc0[3]*bf2f(M0V.w));                                    \
        rssum0 += (e0+e1) + (e2+e3);                                              \
        bf16x4 pb0 = pack_bf16x4(e0, e1, e2, e3);                                 \
        float f0 = fexp2(acc1[0]*bf2f(M1V.x));                                    \
        float f1 = fexp2(acc1[1]*bf2f(M1V.y));                                    \
        float f2 = fexp2(acc1[2]*bf2f(M1V.z));                                    \
        float f3 = fexp2(acc1[3]*bf2f(M1V.w));                                    \
        rssum1 += (f0+f1) + (f2+f3);                                              \
        bf16x4 pb1 = pack_bf16x4(f0, f1, f2, f3);                                 \
        bf16x4 vlo; vlo[0]=VV[0]; vlo[1]=VV[1]; vlo[2]=VV[2]; vlo[3]=VV[3];       \
        bf16x4 vhi; vhi[0]=VV[4]; vhi[1]=VV[5]; vhi[2]=VV[6]; vhi[3]=VV[7];       \
        pv00 = mfma16(pb0, vlo, pv00);                                            \
        pv01 = mfma16(pb0, vhi, pv01);                                            \
        pv10 = mfma16(pb1, vlo, pv10);                                            \
        pv11 = mfma16(pb1, vhi, pv11);                                            \
    }

__global__ __launch_bounds__(256, 4) void k_ctx(const short* __restrict__ Qb,
    const short* __restrict__ Kf, const short* __restrict__ Vf,
    const short* __restrict__ maskf, short* __restrict__ ctxb, float* __restrict__ denomG)
{
    int tid  = threadIdx.x;
    int lane = tid & 63;
    int w    = tid >> 6;          // wave 0..3
    int b    = blockIdx.x & 15;   // b-inner: XCD pinning (b%8)
    int qh   = blockIdx.x >> 4;   // 0..65
    int qt32 = qh >> 1;           // 0..32
    int head = (qh & 1)*4 + w;
    int q0   = qt32 * 32;
    int lr   = lane & 15;
    int lg   = lane >> 4;

    const int bh = b*H_ + head;
    bf16x8 qf0 = *(const bf16x8*)(Qb + ((size_t)bh*S_ + q0 + lr)*DK_ + lg*8);
    bf16x8 qf1 = *(const bf16x8*)(Qb + ((size_t)bh*S_ + q0 + 16 + lr)*DK_ + lg*8);
    const short* Kp  = Kf + (((size_t)bh*NKT_) << 9) + lane*8;         // + t*512
    const short* Vp  = Vf + (((size_t)bh*NKT_) << 9) + lane*8;         // + t*512
    const short* Mp0 = maskf + (((size_t)(qt32*2  )*NKT_) << 8) + lane*4;
    const short* Mp1 = maskf + (((size_t)(qt32*2+1)*NKT_) << 8) + lane*4;

    float rssum0 = 0.f, rssum1 = 0.f;
    f32x4 pv00 = {0.f,0.f,0.f,0.f}, pv01 = {0.f,0.f,0.f,0.f};
    f32x4 pv10 = {0.f,0.f,0.f,0.f}, pv11 = {0.f,0.f,0.f,0.f};

    for (int g = 0; g < 22; ++g) {
        int tb = g * 3;
        // ---- load batch: 12 lane-coalesced loads for 3 tiles ----
        bf16x8 K[3], VV[3]; ushort4 M0[3], M1[3];
        #pragma unroll
        for (int c = 0; c < 3; ++c) {
            int t = tb + c;
            K[c]  = *(const bf16x8*)(Kp + (unsigned)t*512);
            VV[c] = *(const bf16x8*)(Vp + (unsigned)t*512);
            M0[c] = *(const ushort4*)(Mp0 + (unsigned)t*256);
            M1[c] = *(const ushort4*)(Mp1 + (unsigned)t*256);
        }
        #pragma unroll
        for (int c = 0; c < 3; ++c) {
            CTX_TILE2(K[c], M0[c], M1[c], VV[c])
        }
    }

    rssum0 += __shfl_xor(rssum0, 16, 64);
    rssum0 += __shfl_xor(rssum0, 32, 64);
    rssum1 += __shfl_xor(rssum1, 16, 64);
    rssum1 += __shfl_xor(rssum1, 32, 64);
    float rd0 = 1.f / rssum0;
    float rd1 = 1.f / rssum1;
    if (lane < 16) {
        denomG[(size_t)bh*S_ + q0 + lane]      = rd0;
        denomG[(size_t)bh*S_ + q0 + 16 + lane] = rd1;
    }

    #pragma unroll
    for (int r = 0; r < 4; ++r) {
        float rdq0 = __shfl(rd0, 4*lg + r, 64);
        float rdq1 = __shfl(rd1, 4*lg + r, 64);
        size_t off0 = ((size_t)b*S_ + q0 + 4*lg + r)*DM_ + head*DK_ + lr;
        size_t off1 = ((size_t)b*S_ + q0 + 16 + 4*lg + r)*DM_ + head*DK_ + lr;
        ctxb[off0]      = f2bf(pv00[r] * rdq0);
        ctxb[off0 + 16] = f2bf(pv01[r] * rdq0);
        ctxb[off1]      = f2bf(pv10[r] * rdq1);
        ctxb[off1 + 16] = f2bf(pv11[r] * rdq1);
    }
}

// ---------------- kernel B: att by score recompute — maskf-aligned orientation ----------------
__global__ __launch_bounds__(256, 4) void k_att(const short* __restrict__ Qb,
    const short* __restrict__ Kf, const short* __restrict__ maskf,
    const float* __restrict__ denomG, float* __restrict__ att)
{
    int tid  = threadIdx.x;
    int lane = tid & 63;
    int w    = tid >> 6;
    int b    = blockIdx.x & 15;       // b-inner: XCD pinning
    int qt   = blockIdx.x >> 4;
    int q0   = qt * 16;
    int lr   = lane & 15;
    int lg   = lane >> 4;

    float rdv[8];
    #pragma unroll
    for (int h = 0; h < 8; ++h)
        rdv[h] = denomG[(size_t)(b*H_+h)*S_ + q0 + lr] * 0.125f;

    bf16x8 qf[8];
    #pragma unroll
    for (int h = 0; h < 8; ++h)
        qf[h] = *(const bf16x8*)(Qb + ((size_t)(b*H_+h)*S_ + q0+lr)*DK_ + lg*8);

    int nt = (w < 2) ? 17 : 16;
    for (int t = 0; t < nt; ++t) {
        int kt = t*4 + w;
        int k0 = kt*16;
        bf16x8 kf[8];
        #pragma unroll
        for (int h = 0; h < 8; ++h)
            kf[h] = *(const bf16x8*)(Kf + (((size_t)(b*H_+h)*NKT_ + kt) << 9) + lane*8);
        ushort4 mq = *(const ushort4*)(maskf + (((size_t)qt*NKT_ + kt) << 8) + lane*4);
        float m0 = bf2f(mq.x), m1 = bf2f(mq.y), m2 = bf2f(mq.z), m3 = bf2f(mq.w);
        f32x4 a = {0.f,0.f,0.f,0.f};
        #pragma unroll
        for (int h = 0; h < 8; ++h) {
            f32x4 s = {0.f,0.f,0.f,0.f};
            s = __builtin_amdgcn_mfma_f32_16x16x32_bf16(kf[h], qf[h], s, 0, 0, 0);
            a[0] = fmaf(fexp2(s[0]*m0), rdv[h], a[0]);
            a[1] = fmaf(fexp2(s[1]*m1), rdv[h], a[1]);
            a[2] = fmaf(fexp2(s[2]*m2), rdv[h], a[2]);
            a[3] = fmaf(fexp2(s[3]*m3), rdv[h], a[3]);
        }
        float4 o4 = make_float4(a[0], a[1], a[2], a[3]);
        *(float4*)&att[((size_t)b*S_ + q0+lr)*S_ + k0 + 4*lg] = o4;
    }
}

// ---------------- out projection via MFMA (no LDS) ----------------
__global__ __launch_bounds__(256, 2) void k_outproj(const short* __restrict__ ctxb,
    const short* __restrict__ WoB, const float* __restrict__ bias, float* __restrict__ out)
{
    int tid  = threadIdx.x;
    int lane = tid & 63;
    int w    = tid >> 6;
    int lr   = lane & 15;
    int lg   = lane >> 4;
    int r0   = blockIdx.x * 16;

    bf16x8 cf[8];
    #pragma unroll
    for (int kk = 0; kk < 8; ++kk)
        cf[kk] = *(const bf16x8*)(ctxb + (size_t)(r0+lr)*DM_ + kk*32 + lg*8);

    #pragma unroll
    for (int ct = 0; ct < 4; ++ct) {
        int tb = (w + ct*4) * 16;
        const short* Wp = WoB + (size_t)(tb+lr)*DM_ + lg*8;
        f32x4 acc = {0.f,0.f,0.f,0.f};
        #pragma unroll
        for (int kk = 0; kk < 8; ++kk) {
            bf16x8 wf = *(const bf16x8*)(Wp + kk*32);
            acc = __builtin_amdgcn_mfma_f32_16x16x32_bf16(wf, cf[kk], acc, 0, 0, 0);
        }
        float4 b4 = *(const float4*)&bias[tb + lg*4];
        float4 o4 = make_float4(acc[0]+b4.x, acc[1]+b4.y, acc[2]+b4.z, acc[3]+b4.w);
        *(float4*)&out[(size_t)(r0+lr)*DM_ + tb + lg*4] = o4;
    }
}

extern "C" void kernel_launch(void* const* d_in, const int* in_sizes, int n_in,
                              void* d_out, int out_size, void* d_ws, size_t ws_size,
                              hipStream_t stream)
{
    (void)in_sizes; (void)n_in; (void)out_size; (void)ws_size;
    const float* src  = (const float*)d_in[0];
    const float* Wtq  = (const float*)d_in[1];
    const float* Wtk  = (const float*)d_in[2];
    const float* Wtv  = (const float*)d_in[3];
    const float* Wvq  = (const float*)d_in[4];
    const float* Wvk  = (const float*)d_in[5];
    const float* Wvv  = (const float*)d_in[6];
    const float* lvr  = (const float*)d_in[7];
    const float* Wout = (const float*)d_in[8];
    const float* bout = (const float*)d_in[9];
    const int*   rid  = (const int*)d_in[10];
    const int*   cid  = (const int*)d_in[11];

    const size_t QKV_SH = (size_t)B_*H_*S_*DK_;      // Qb shorts
    const size_t KF_SH  = (size_t)B_*H_*NKT_*512;    // Kf shorts
    const size_t VF_SH  = (size_t)B_*H_*NKT_*512;    // Vf shorts
    const size_t CTX_SH = (size_t)B_*S_*DM_;

    float* ws       = (float*)d_ws;
    float* partials = ws;                             // MASK_BLKS
    float* denomG   = partials + MASK_BLKS;           // B*H*S
    short* maskf    = (short*)(denomG + (size_t)B_*H_*S_);
    short* Qb       = maskf + SS_;
    short* Kf       = Qb + QKV_SH;
    short* Vf       = Kf + KF_SH;
    short* ctxb     = Vf + VF_SH;
    short* WTall    = ctxb + CTX_SH;                  // 6*65536
    short* WoB      = WTall + 6*65536;

    float* out  = (float*)d_out;
    float* att  = out + (size_t)B_*S_*DM_;
    float* loss = att + (size_t)B_*S_*S_;

    k_mask<<<MASK_BLKS, 256, 0, stream>>>(lvr, rid, cid, maskf, partials);
    k_wprep<<<7*256, 256, 0, stream>>>(Wtq, Wtk, Wtv, Wvq, Wvk, Wvv, Wout, WTall, WoB);
    k_qkv<<<(B_*TXT_)/16, 256, 0, stream>>>(src, WTall, WTall+65536, WTall+2*65536,
                                            Qb, Kf, Vf, 1);
    k_qkv<<<(B_*VID_)/16, 256, 0, stream>>>(src, WTall+3*65536, WTall+4*65536, WTall+5*65536,
                                            Qb, Kf, Vf, 0);
    k_ctx<<<B_*NQT_, 256, 0, stream>>>(Qb, Kf, Vf, maskf, ctxb, denomG);
    k_att<<<B_*NQT_, 256, 0, stream>>>(Qb, Kf, maskf, denomG, att);
    k_outproj<<<(B_*S_)/16, 256, 0, stream>>>(ctxb, WoB, bout, out);
    k_loss<<<1, 256, 0, stream>>>(partials, loss);
}

// Round 17
// 171.095 us; speedup vs baseline: 1.4113x; 1.2474x over previous
//
#include <hip/hip_runtime.h>
#include <math.h>

#define B_   16
#define S_   1056
#define DM_  256
#define H_   8
#define DK_  32
#define TXT_ 32
#define VID_ 1024
#define SS_  (S_*S_)          // 1115136
#define NQT_ 66               // q-tiles of 16 rows
#define NKT_ 66               // k-tiles of 16
#define MASK_BLKS 1089        // (66*66*64)/256

#define LOG2_10000f 13.28771237954945f
#define LOG2_GAMMAf (-0.15200309344504995f)   // log2(0.9)
#define RSQRT_DKf   0.17677669529663687f      // 1/sqrt(32)
#define TWO_PIf     6.283185307179586f
#define LOG2Ef      1.4426950408889634f

typedef __attribute__((ext_vector_type(8))) short bf16x8;
typedef __attribute__((ext_vector_type(4))) short bf16x4;
typedef __attribute__((ext_vector_type(4))) float f32x4;

__device__ __forceinline__ short f2bf(float f){
    unsigned u = __float_as_uint(f);
    unsigned r = u + 0x7FFFu + ((u >> 16) & 1u);   // RNE
    return (short)(r >> 16);
}
__device__ __forceinline__ float bf2f(unsigned short s){
    return __uint_as_float(((unsigned)s) << 16);
}
__device__ __forceinline__ float fexp2(float x){
#if __has_builtin(__builtin_amdgcn_exp2f)
    return __builtin_amdgcn_exp2f(x);
#else
    return exp2f(x);
#endif
}
__device__ __forceinline__ bf16x4 pack_bf16x4(float e0, float e1, float e2, float e3){
    unsigned w0, w1;
    asm("v_cvt_pk_bf16_f32 %0, %1, %2" : "=v"(w0) : "v"(e0), "v"(e1));
    asm("v_cvt_pk_bf16_f32 %0, %1, %2" : "=v"(w1) : "v"(e2), "v"(e3));
    uint2 u = make_uint2(w0, w1);
    return *(bf16x4*)&u;
}

// K=16 bf16 MFMA: A-frag lane l holds A[row=l%16][k=4(l/16)+j] — matches the
// QK^T D-fragment, so P feeds PV in-lane.
__device__ __forceinline__ f32x4 mfma16(bf16x4 a, bf16x4 b, f32x4 c){
#if __has_builtin(__builtin_amdgcn_mfma_f32_16x16x16bf16_1k)
    return __builtin_amdgcn_mfma_f32_16x16x16bf16_1k(a, b, c, 0, 0, 0);
#else
    f32x4 d = c;
    asm("v_mfma_f32_16x16x16_bf16 %0, %1, %2, %0" : "+v"(d) : "v"(a), "v"(b));
    return d;
#endif
}

// ---------------- mask: fragment-order maskf (pre-scaled by log2e) + loss partials ----------------
__global__ __launch_bounds__(256) void k_mask(const float* __restrict__ lvr,
                       const int* __restrict__ row_idx, const int* __restrict__ col_idx,
                       short* __restrict__ maskf, float* __restrict__ partials)
{
    int T  = blockIdx.x*256 + threadIdx.x;
    int l  = T & 63;
    int qk = T >> 6;                  // qt*66 + kt
    int qt = qk / 66;
    int kt = qk - qt*66;
    int i  = qt*16 + (l & 15);
    int j0 = kt*16 + 4*(l >> 4);
    size_t idx = (size_t)i*S_ + j0;
    int4 ri4 = *(const int4*)&row_idx[idx];
    int4 ci4 = *(const int4*)&col_idx[idx];
    int rr[4] = {ri4.x, ri4.y, ri4.z, ri4.w};
    int cc[4] = {ci4.x, ci4.y, ci4.z, ci4.w};
    float vrs = 0.f;
    short4 mq;
    short* mp = (short*)&mq;
    #pragma unroll
    for (int jj = 0; jj < 4; ++jj) {
        int j = j0 + jj;
        float vr, lm;
        if (i == j) { vr = 0.f; lm = 1.f; }
        else {
            float t = lvr[(size_t)rr[jj]*VID_ + cc[jj]];
            float sg = 1.f/(1.f + expf(-t));
            vr = sg; lm = sg;
        }
        float dmat = (i >= j) ? exp2f((float)(i-j)*LOG2_GAMMAf) : 0.f;
        mp[jj] = f2bf(dmat * lm * LOG2Ef);   // exp(s*m) = exp2(s*m')
        vrs += vr;
    }
    *(short4*)&maskf[(size_t)qk*256 + l*4] = mq;

    float s = vrs;
    #pragma unroll
    for (int m=1; m<64; m<<=1) s += __shfl_xor(s, m, 64);
    __shared__ float ws4[4];
    if ((threadIdx.x & 63) == 0) ws4[threadIdx.x>>6] = s;
    __syncthreads();
    if (threadIdx.x == 0) partials[blockIdx.x] = ws4[0]+ws4[1]+ws4[2]+ws4[3];
}

__global__ __launch_bounds__(256) void k_loss(const float* __restrict__ partials,
                                              float* __restrict__ out_loss)
{
    float s = 0.f;
    for (int i = threadIdx.x; i < MASK_BLKS; i += 256) s += partials[i];
    #pragma unroll
    for (int m=1; m<64; m<<=1) s += __shfl_xor(s, m, 64);
    __shared__ float ws4[4];
    if ((threadIdx.x & 63) == 0) ws4[threadIdx.x>>6] = s;
    __syncthreads();
    if (threadIdx.x == 0) out_loss[0] = (ws4[0]+ws4[1]+ws4[2]+ws4[3]) * (1.f/(float)SS_);
}

// ---------------- weight prep -> MFMA-fragment tiles ----------------
// Wf tile (seg, tb16, kk): 1KB; lane l holds WT[o=tb16*16+l%16][e=kk*32+8*(l/16)..+7].
// Same layout for WoF (Wout[o][e], no transpose). Fragment lane math:
// o=r: tb16=r>>4, lr=r&15 ; e=tid: kk=tid>>5, lg=(tid>>3)&3, j=tid&7.
__global__ __launch_bounds__(256) void k_wprep(
    const float* __restrict__ Wtq, const float* __restrict__ Wtk, const float* __restrict__ Wtv,
    const float* __restrict__ Wvq, const float* __restrict__ Wvk, const float* __restrict__ Wvv,
    const float* __restrict__ Wout, short* __restrict__ Wf, short* __restrict__ WoF)
{
    int seg = blockIdx.x >> 8;
    int r   = blockIdx.x & 255;
    int tid = threadIdx.x;
    int tb16 = r >> 4, lr = r & 15;
    int kk = tid >> 5, lg = (tid >> 3) & 3, j = tid & 7;
    size_t off = (((size_t)tb16*8 + kk) << 9) + (lr + 16*lg)*8 + j;
    if (seg == 6) {
        WoF[off] = f2bf(Wout[r*256 + tid]);                 // Wout[o][e]
    } else {
        const float* Wsrc = seg==0?Wtq: seg==1?Wtk: seg==2?Wtv: seg==3?Wvq: seg==4?Wvk: Wvv;
        Wf[((size_t)seg << 16) + off] = f2bf(Wsrc[tid*256 + r]);
    }
}

// ---------------- QKV projection via MFMA — fragment-tiled W loads ----------------
__global__ __launch_bounds__(256, 2) void k_qkv(const float* __restrict__ src,
    const short* __restrict__ WFq, const short* __restrict__ WFk, const short* __restrict__ WFv,
    short* __restrict__ Qb, short* __restrict__ Kf, short* __restrict__ Vf, int is_txt)
{
    __shared__ __align__(16) short xb[3][16][256];   // 24 KB
    __shared__ float invf[128];
    __shared__ float lbs[128];
    int tid = threadIdx.x;
    int r0 = blockIdx.x * 16;
    int b, srow0;
    if (is_txt) { b = r0 >> 5;  srow0 = r0 & 31; }
    else        { b = r0 >> 10; srow0 = TXT_ + (r0 & 1023); }
    int t16 = srow0 >> 4;

    if (tid < 128) {
        float fk = (float)tid;
        invf[tid] = exp2f(-fk*(1.f/128.f)*LOG2_10000f);
        lbs[tid]  = log2f((2.f*fk + 102.4f) * (1.f/358.4f));
    }
    __syncthreads();

    #pragma unroll
    for (int it = 0; it < 8; ++it) {
        int task = it*256 + tid;
        int k  = task >> 4;
        int rr = task & 15;
        int srow = srow0 + rr;
        float2 x01 = ((const float2*)(src + ((size_t)b*S_ + srow)*DM_))[k];
        float a0, a1, c0, c1;
        if (is_txt) {
            float xe  = (float)(srow + 1) * (TWO_PIf/(32.f + 1e-6f));
            float arg = xe * invf[k];
            float sn = __sinf(arg), cs = __cosf(arg);
            a0 = x01.x + sn; a1 = x01.y + cs;
            c0 = a0; c1 = a1;
        } else {
            int l = srow - TXT_;
            float arg = (float)l * invf[k];
            float sn = __sinf(arg), cs = __cosf(arg);
            float scale = exp2f((float)l*(1.f/512.f)*lbs[k]);
            float rsc = 1.f/scale;
            float y0 = x01.x*cs - x01.y*sn;
            float y1 = x01.y*cs + x01.x*sn;
            a0 = y0*scale; a1 = y1*scale;
            c0 = y0*rsc;   c1 = y1*rsc;
        }
        int col = (2*k) ^ ((rr&7)<<3);
        *(short2*)&xb[0][rr][col] = make_short2(f2bf(a0), f2bf(a1));
        *(short2*)&xb[1][rr][col] = make_short2(f2bf(c0), f2bf(c1));
        *(short2*)&xb[2][rr][col] = make_short2(f2bf(x01.x), f2bf(x01.y));
    }
    __syncthreads();

    int lane = tid & 63;
    int w    = tid >> 6;
    int lr   = lane & 15;
    int lg   = lane >> 4;
    int swzl = (lr & 7) << 3;

    const short* WFs[3] = {WFq, WFk, WFv};
    #pragma unroll
    for (int m = 0; m < 3; ++m) {
        bf16x8 xf[8];
        #pragma unroll
        for (int kk = 0; kk < 8; ++kk)
            xf[kk] = *(const bf16x8*)&xb[m][lr][(kk*32 + lg*8) ^ swzl];
        #pragma unroll
        for (int ct = 0; ct < 4; ++ct) {
            int tb16 = w + ct*4;
            int tb   = tb16 * 16;
            const short* Wp = WFs[m] + (((size_t)tb16*8) << 9) + lane*8;
            f32x4 acc = {0.f,0.f,0.f,0.f};
            if (m < 2) {
                #pragma unroll
                for (int kk = 0; kk < 8; ++kk) {
                    bf16x8 wf = *(const bf16x8*)(Wp + (kk << 9));
                    acc = __builtin_amdgcn_mfma_f32_16x16x32_bf16(wf, xf[kk], acc, 0, 0, 0);
                }
                int h  = tb >> 5;
                int d0 = (tb & 31) + lg*4;
                short4 s4;
                if (m == 0) {
                    s4.x=f2bf(acc[0]*RSQRT_DKf); s4.y=f2bf(acc[1]*RSQRT_DKf);
                    s4.z=f2bf(acc[2]*RSQRT_DKf); s4.w=f2bf(acc[3]*RSQRT_DKf);
                    size_t off = ((size_t)(b*H_+h)*S_ + srow0+lr)*DK_ + d0;
                    *(short4*)&Qb[off] = s4;
                } else {
                    s4.x=f2bf(acc[0]); s4.y=f2bf(acc[1]);
                    s4.z=f2bf(acc[2]); s4.w=f2bf(acc[3]);
                    int lK = lr + 16*(d0 >> 3);
                    *(short4*)&Kf[((((size_t)(b*H_+h)*NKT_ + t16) << 9)) + lK*8 + (d0 & 7)] = s4;
                }
            } else {
                #pragma unroll
                for (int kk = 0; kk < 8; ++kk) {
                    bf16x8 wf = *(const bf16x8*)(Wp + (kk << 9));
                    acc = __builtin_amdgcn_mfma_f32_16x16x32_bf16(xf[kk], wf, acc, 0, 0, 0);
                }
                int o = tb + lr;
                int h = o >> 5;
                int dh = (tb >> 4) & 1;
                short4 s4;
                s4.x=f2bf(acc[0]); s4.y=f2bf(acc[1]);
                s4.z=f2bf(acc[2]); s4.w=f2bf(acc[3]);
                *(short4*)&Vf[((((size_t)(b*H_+h)*NKT_ + t16)) << 9) + lane*8 + dh*4] = s4;
            }
        }
    }
}

// ---------------- kernel A: denominators + ctx — 32 q/wave; ctx stored fragment-order ----------------
#define CTX_TILE2(KF, M0V, M1V, VV)                                               \
    {                                                                             \
        f32x4 acc0 = {0.f,0.f,0.f,0.f};                                           \
        acc0 = __builtin_amdgcn_mfma_f32_16x16x32_bf16(KF, qf0, acc0, 0, 0, 0);   \
        f32x4 acc1 = {0.f,0.f,0.f,0.f};                                           \
        acc1 = __builtin_amdgcn_mfma_f32_16x16x32_bf16(KF, qf1, acc1, 0, 0, 0);   \
        float e0 = fexp2(acc0[0]*bf2f(M0V.x));                                    \
        float e1 = fexp2(acc0[1]*bf2f(M0V.y));                                    \
        float e2 = fexp2(acc0[2]*bf2f(M0V.z));                                    \
        float e3 = fexp2(acc0[3]*bf2f(M0V.w));                                    \
        rssum0 += (e0+e1) + (e2+e3);                                              \
        bf16x4 pb0 = pack_bf16x4(e0, e1, e2, e3);                                 \
        float f0 = fexp2(acc1[0]*bf2f(M1V.x));                                    \
        float f1 = fexp2(acc1[1]*bf2f(M1V.y));                                    \
        float f2 = fexp2(acc1[2]*bf2f(M1V.z));                                    \
        float f3 = fexp2(acc1[3]*bf2f(M1V.w));                                    \
        rssum1 += (f0+f1) + (f2+f3);                                              \
        bf16x4 pb1 = pack_bf16x4(f0, f1, f2, f3);                                 \
        bf16x4 vlo; vlo[0]=VV[0]; vlo[1]=VV[1]; vlo[2]=VV[2]; vlo[3]=VV[3];       \
        bf16x4 vhi; vhi[0]=VV[4]; vhi[1]=VV[5]; vhi[2]=VV[6]; vhi[3]=VV[7];       \
        pv00 = mfma16(pb0, vlo, pv00);                                            \
        pv01 = mfma16(pb0, vhi, pv01);                                            \
        pv10 = mfma16(pb1, vlo, pv10);                                            \
        pv11 = mfma16(pb1, vhi, pv11);                                            \
    }

__global__ __launch_bounds__(256, 4) void k_ctx(const short* __restrict__ Qb,
    const short* __restrict__ Kf, const short* __restrict__ Vf,
    const short* __restrict__ maskf, short* __restrict__ ctxf, float* __restrict__ denomG)
{
    int tid  = threadIdx.x;
    int lane = tid & 63;
    int w    = tid >> 6;          // wave 0..3
    int b    = blockIdx.x & 15;   // b-inner: XCD pinning (b%8)
    int qh   = blockIdx.x >> 4;   // 0..65
    int qt32 = qh >> 1;           // 0..32
    int head = (qh & 1)*4 + w;
    int q0   = qt32 * 32;
    int lr   = lane & 15;
    int lg   = lane >> 4;

    const int bh = b*H_ + head;
    bf16x8 qf0 = *(const bf16x8*)(Qb + ((size_t)bh*S_ + q0 + lr)*DK_ + lg*8);
    bf16x8 qf1 = *(const bf16x8*)(Qb + ((size_t)bh*S_ + q0 + 16 + lr)*DK_ + lg*8);
    const short* Kp  = Kf + (((size_t)bh*NKT_) << 9) + lane*8;         // + t*512
    const short* Vp  = Vf + (((size_t)bh*NKT_) << 9) + lane*8;         // + t*512
    const short* Mp0 = maskf + (((size_t)(qt32*2  )*NKT_) << 8) + lane*4;
    const short* Mp1 = maskf + (((size_t)(qt32*2+1)*NKT_) << 8) + lane*4;

    float rssum0 = 0.f, rssum1 = 0.f;
    f32x4 pv00 = {0.f,0.f,0.f,0.f}, pv01 = {0.f,0.f,0.f,0.f};
    f32x4 pv10 = {0.f,0.f,0.f,0.f}, pv11 = {0.f,0.f,0.f,0.f};

    for (int g = 0; g < 22; ++g) {
        int tb = g * 3;
        bf16x8 K[3], VV[3]; ushort4 M0[3], M1[3];
        #pragma unroll
        for (int c = 0; c < 3; ++c) {
            int t = tb + c;
            K[c]  = *(const bf16x8*)(Kp + (unsigned)t*512);
            VV[c] = *(const bf16x8*)(Vp + (unsigned)t*512);
            M0[c] = *(const ushort4*)(Mp0 + (unsigned)t*256);
            M1[c] = *(const ushort4*)(Mp1 + (unsigned)t*256);
        }
        #pragma unroll
        for (int c = 0; c < 3; ++c) {
            CTX_TILE2(K[c], M0[c], M1[c], VV[c])
        }
    }

    rssum0 += __shfl_xor(rssum0, 16, 64);
    rssum0 += __shfl_xor(rssum0, 32, 64);
    rssum1 += __shfl_xor(rssum1, 16, 64);
    rssum1 += __shfl_xor(rssum1, 32, 64);
    float rd0 = 1.f / rssum0;
    float rd1 = 1.f / rssum1;
    if (lane < 16) {
        denomG[(size_t)bh*S_ + q0 + lane]      = rd0;
        denomG[(size_t)bh*S_ + q0 + 16 + lane] = rd1;
    }

    // ctxf fragment store: tile (b*66 + q>>4, kk=head); lane' = (q&15)+16*(d>>3), j=d&7.
    size_t baseA = ((((size_t)b*NQT_ + qt32*2    )*8 + head) << 9);
    size_t baseB = ((((size_t)b*NQT_ + qt32*2 + 1)*8 + head) << 9);
    int j   = lr & 7;
    int lgl = lr >> 3;         // d=lr -> lg'=lr>>3 ; d=16+lr -> lg'=2+(lr>>3)
    #pragma unroll
    for (int r = 0; r < 4; ++r) {
        float rdq0 = __shfl(rd0, 4*lg + r, 64);
        float rdq1 = __shfl(rd1, 4*lg + r, 64);
        int qm = 4*lg + r;
        ctxf[baseA + (qm + 16*lgl    )*8 + j] = f2bf(pv00[r] * rdq0);
        ctxf[baseA + (qm + 16*(2+lgl))*8 + j] = f2bf(pv01[r] * rdq0);
        ctxf[baseB + (qm + 16*lgl    )*8 + j] = f2bf(pv10[r] * rdq1);
        ctxf[baseB + (qm + 16*(2+lgl))*8 + j] = f2bf(pv11[r] * rdq1);
    }
}

// ---------------- kernel B: att by score recompute — maskf-aligned orientation ----------------
__global__ __launch_bounds__(256, 4) void k_att(const short* __restrict__ Qb,
    const short* __restrict__ Kf, const short* __restrict__ maskf,
    const float* __restrict__ denomG, float* __restrict__ att)
{
    int tid  = threadIdx.x;
    int lane = tid & 63;
    int w    = tid >> 6;
    int b    = blockIdx.x & 15;       // b-inner: XCD pinning
    int qt   = blockIdx.x >> 4;
    int q0   = qt * 16;
    int lr   = lane & 15;
    int lg   = lane >> 4;

    float rdv[8];
    #pragma unroll
    for (int h = 0; h < 8; ++h)
        rdv[h] = denomG[(size_t)(b*H_+h)*S_ + q0 + lr] * 0.125f;

    bf16x8 qf[8];
    #pragma unroll
    for (int h = 0; h < 8; ++h)
        qf[h] = *(const bf16x8*)(Qb + ((size_t)(b*H_+h)*S_ + q0+lr)*DK_ + lg*8);

    int nt = (w < 2) ? 17 : 16;
    for (int t = 0; t < nt; ++t) {
        int kt = t*4 + w;
        int k0 = kt*16;
        bf16x8 kf[8];
        #pragma unroll
        for (int h = 0; h < 8; ++h)
            kf[h] = *(const bf16x8*)(Kf + (((size_t)(b*H_+h)*NKT_ + kt) << 9) + lane*8);
        ushort4 mq = *(const ushort4*)(maskf + (((size_t)qt*NKT_ + kt) << 8) + lane*4);
        float m0 = bf2f(mq.x), m1 = bf2f(mq.y), m2 = bf2f(mq.z), m3 = bf2f(mq.w);
        f32x4 a = {0.f,0.f,0.f,0.f};
        #pragma unroll
        for (int h = 0; h < 8; ++h) {
            f32x4 s = {0.f,0.f,0.f,0.f};
            s = __builtin_amdgcn_mfma_f32_16x16x32_bf16(kf[h], qf[h], s, 0, 0, 0);
            a[0] = fmaf(fexp2(s[0]*m0), rdv[h], a[0]);
            a[1] = fmaf(fexp2(s[1]*m1), rdv[h], a[1]);
            a[2] = fmaf(fexp2(s[2]*m2), rdv[h], a[2]);
            a[3] = fmaf(fexp2(s[3]*m3), rdv[h], a[3]);
        }
        float4 o4 = make_float4(a[0], a[1], a[2], a[3]);
        *(float4*)&att[((size_t)b*S_ + q0+lr)*S_ + k0 + 4*lg] = o4;
    }
}

// ---------------- out projection via MFMA — fragment-tiled W and ctx loads ----------------
__global__ __launch_bounds__(256, 2) void k_outproj(const short* __restrict__ ctxf,
    const short* __restrict__ WoF, const float* __restrict__ bias, float* __restrict__ out)
{
    int tid  = threadIdx.x;
    int lane = tid & 63;
    int w    = tid >> 6;
    int lr   = lane & 15;
    int lg   = lane >> 4;
    int r0   = blockIdx.x * 16;       // global row tile index = blockIdx.x = b*66 + qt16

    bf16x8 cf[8];
    #pragma unroll
    for (int kk = 0; kk < 8; ++kk)
        cf[kk] = *(const bf16x8*)(ctxf + (((size_t)blockIdx.x*8 + kk) << 9) + lane*8);

    #pragma unroll
    for (int ct = 0; ct < 4; ++ct) {
        int tb16 = w + ct*4;
        int tb   = tb16 * 16;
        f32x4 acc = {0.f,0.f,0.f,0.f};
        #pragma unroll
        for (int kk = 0; kk < 8; ++kk) {
            bf16x8 wf = *(const bf16x8*)(WoF + (((size_t)tb16*8 + kk) << 9) + lane*8);
            acc = __builtin_amdgcn_mfma_f32_16x16x32_bf16(wf, cf[kk], acc, 0, 0, 0);
        }
        float4 b4 = *(const float4*)&bias[tb + lg*4];
        float4 o4 = make_float4(acc[0]+b4.x, acc[1]+b4.y, acc[2]+b4.z, acc[3]+b4.w);
        *(float4*)&out[(size_t)(r0+lr)*DM_ + tb + lg*4] = o4;
    }
}

extern "C" void kernel_launch(void* const* d_in, const int* in_sizes, int n_in,
                              void* d_out, int out_size, void* d_ws, size_t ws_size,
                              hipStream_t stream)
{
    (void)in_sizes; (void)n_in; (void)out_size; (void)ws_size;
    const float* src  = (const float*)d_in[0];
    const float* Wtq  = (const float*)d_in[1];
    const float* Wtk  = (const float*)d_in[2];
    const float* Wtv  = (const float*)d_in[3];
    const float* Wvq  = (const float*)d_in[4];
    const float* Wvk  = (const float*)d_in[5];
    const float* Wvv  = (const float*)d_in[6];
    const float* lvr  = (const float*)d_in[7];
    const float* Wout = (const float*)d_in[8];
    const float* bout = (const float*)d_in[9];
    const int*   rid  = (const int*)d_in[10];
    const int*   cid  = (const int*)d_in[11];

    const size_t QKV_SH = (size_t)B_*H_*S_*DK_;      // Qb shorts
    const size_t KF_SH  = (size_t)B_*H_*NKT_*512;    // Kf shorts
    const size_t VF_SH  = (size_t)B_*H_*NKT_*512;    // Vf shorts
    const size_t CTX_SH = (size_t)B_*S_*DM_;

    float* ws       = (float*)d_ws;
    float* partials = ws;                             // MASK_BLKS
    float* denomG   = partials + MASK_BLKS;           // B*H*S
    short* maskf    = (short*)(denomG + (size_t)B_*H_*S_);
    short* Qb       = maskf + SS_;
    short* Kf       = Qb + QKV_SH;
    short* Vf       = Kf + KF_SH;
    short* ctxf     = Vf + VF_SH;
    short* Wf       = ctxf + CTX_SH;                  // 6*65536
    short* WoF      = Wf + 6*65536;

    float* out  = (float*)d_out;
    float* att  = out + (size_t)B_*S_*DM_;
    float* loss = att + (size_t)B_*S_*S_;

    k_mask<<<MASK_BLKS, 256, 0, stream>>>(lvr, rid, cid, maskf, partials);
    k_wprep<<<7*256, 256, 0, stream>>>(Wtq, Wtk, Wtv, Wvq, Wvk, Wvv, Wout, Wf, WoF);
    k_qkv<<<(B_*TXT_)/16, 256, 0, stream>>>(src, Wf, Wf+65536, Wf+2*65536,
                                            Qb, Kf, Vf, 1);
    k_qkv<<<(B_*VID_)/16, 256, 0, stream>>>(src, Wf+3*65536, Wf+4*65536, Wf+5*65536,
                                            Qb, Kf, Vf, 0);
    k_ctx<<<B_*NQT_, 256, 0, stream>>>(Qb, Kf, Vf, maskf, ctxf, denomG);
    k_att<<<B_*NQT_, 256, 0, stream>>>(Qb, Kf, maskf, denomG, att);
    k_outproj<<<(B_*S_)/16, 256, 0, stream>>>(ctxf, WoF, bout, out);
    k_loss<<<1, 256, 0, stream>>>(partials, loss);
}

// Round 18
// 158.599 us; speedup vs baseline: 1.5225x; 1.0788x over previous
//
#include <hip/hip_runtime.h>
#include <math.h>

#define B_   16
#define S_   1056
#define DM_  256
#define H_   8
#define DK_  32
#define TXT_ 32
#define VID_ 1024
#define SS_  (S_*S_)          // 1115136
#define NQT_ 66               // q-tiles of 16 rows
#define NKT_ 66               // k-tiles of 16
#define NQ48_ 22              // q-tiles of 48 rows
#define MASK_BLKS 1089        // (66*66*64)/256

#define LOG2_10000f 13.28771237954945f
#define LOG2_GAMMAf (-0.15200309344504995f)   // log2(0.9)
#define RSQRT_DKf   0.17677669529663687f      // 1/sqrt(32)
#define TWO_PIf     6.283185307179586f
#define LOG2Ef      1.4426950408889634f

typedef __attribute__((ext_vector_type(8))) short bf16x8;
typedef __attribute__((ext_vector_type(4))) short bf16x4;
typedef __attribute__((ext_vector_type(4))) float f32x4;

__device__ __forceinline__ short f2bf(float f){
    unsigned u = __float_as_uint(f);
    unsigned r = u + 0x7FFFu + ((u >> 16) & 1u);   // RNE
    return (short)(r >> 16);
}
__device__ __forceinline__ float bf2f(unsigned short s){
    return __uint_as_float(((unsigned)s) << 16);
}
__device__ __forceinline__ float fexp2(float x){
#if __has_builtin(__builtin_amdgcn_exp2f)
    return __builtin_amdgcn_exp2f(x);
#else
    return exp2f(x);
#endif
}
__device__ __forceinline__ bf16x4 pack_bf16x4(float e0, float e1, float e2, float e3){
    unsigned w0, w1;
    asm("v_cvt_pk_bf16_f32 %0, %1, %2" : "=v"(w0) : "v"(e0), "v"(e1));
    asm("v_cvt_pk_bf16_f32 %0, %1, %2" : "=v"(w1) : "v"(e2), "v"(e3));
    uint2 u = make_uint2(w0, w1);
    return *(bf16x4*)&u;
}

// K=16 bf16 MFMA: A-frag lane l holds A[row=l%16][k=4(l/16)+j] — matches the
// QK^T D-fragment, so P feeds PV in-lane.
__device__ __forceinline__ f32x4 mfma16(bf16x4 a, bf16x4 b, f32x4 c){
#if __has_builtin(__builtin_amdgcn_mfma_f32_16x16x16bf16_1k)
    return __builtin_amdgcn_mfma_f32_16x16x16bf16_1k(a, b, c, 0, 0, 0);
#else
    f32x4 d = c;
    asm("v_mfma_f32_16x16x16_bf16 %0, %1, %2, %0" : "+v"(d) : "v"(a), "v"(b));
    return d;
#endif
}

// ---------------- mask: maskf (q=lr frag, for k_ctx) + maskg (k=lr frag, for k_att) ----------------
__global__ __launch_bounds__(256) void k_mask(const float* __restrict__ lvr,
                       const int* __restrict__ row_idx, const int* __restrict__ col_idx,
                       short* __restrict__ maskf, short* __restrict__ maskg,
                       float* __restrict__ partials)
{
    int T  = blockIdx.x*256 + threadIdx.x;
    int l  = T & 63;
    int qk = T >> 6;                  // qt*66 + kt
    int qt = qk / 66;
    int kt = qk - qt*66;
    int i  = qt*16 + (l & 15);
    int j0 = kt*16 + 4*(l >> 4);
    size_t idx = (size_t)i*S_ + j0;
    int4 ri4 = *(const int4*)&row_idx[idx];
    int4 ci4 = *(const int4*)&col_idx[idx];
    int rr[4] = {ri4.x, ri4.y, ri4.z, ri4.w};
    int cc[4] = {ci4.x, ci4.y, ci4.z, ci4.w};
    float vrs = 0.f;
    short4 mq;
    short* mp = (short*)&mq;
    #pragma unroll
    for (int jj = 0; jj < 4; ++jj) {
        int j = j0 + jj;
        float vr, lm;
        if (i == j) { vr = 0.f; lm = 1.f; }
        else {
            float t = lvr[(size_t)rr[jj]*VID_ + cc[jj]];
            float sg = 1.f/(1.f + expf(-t));
            vr = sg; lm = sg;
        }
        float dmat = (i >= j) ? exp2f((float)(i-j)*LOG2_GAMMAf) : 0.f;
        mp[jj] = f2bf(dmat * lm * LOG2Ef);   // exp(s*m) = exp2(s*m')
        vrs += vr;
    }
    *(short4*)&maskf[(size_t)qk*256 + l*4] = mq;
    // maskg: lane' = (k&15) + 16*((q&15)>>2), slot r' = q&3
    {
        int lq = l & 15;
        int r2 = lq & 3;
        int baseq = (lq >> 2) << 4;
        #pragma unroll
        for (int jj = 0; jj < 4; ++jj) {
            int lanep = 4*(l >> 4) + jj + baseq;
            maskg[(size_t)qk*256 + lanep*4 + r2] = mp[jj];
        }
    }

    float s = vrs;
    #pragma unroll
    for (int m=1; m<64; m<<=1) s += __shfl_xor(s, m, 64);
    __shared__ float ws4[4];
    if ((threadIdx.x & 63) == 0) ws4[threadIdx.x>>6] = s;
    __syncthreads();
    if (threadIdx.x == 0) partials[blockIdx.x] = ws4[0]+ws4[1]+ws4[2]+ws4[3];
}

__global__ __launch_bounds__(256) void k_loss(const float* __restrict__ partials,
                                              float* __restrict__ out_loss)
{
    float s = 0.f;
    for (int i = threadIdx.x; i < MASK_BLKS; i += 256) s += partials[i];
    #pragma unroll
    for (int m=1; m<64; m<<=1) s += __shfl_xor(s, m, 64);
    __shared__ float ws4[4];
    if ((threadIdx.x & 63) == 0) ws4[threadIdx.x>>6] = s;
    __syncthreads();
    if (threadIdx.x == 0) out_loss[0] = (ws4[0]+ws4[1]+ws4[2]+ws4[3]) * (1.f/(float)SS_);
}

// ---------------- weight prep -> MFMA-fragment tiles ----------------
__global__ __launch_bounds__(256) void k_wprep(
    const float* __restrict__ Wtq, const float* __restrict__ Wtk, const float* __restrict__ Wtv,
    const float* __restrict__ Wvq, const float* __restrict__ Wvk, const float* __restrict__ Wvv,
    const float* __restrict__ Wout, short* __restrict__ Wf, short* __restrict__ WoF)
{
    int seg = blockIdx.x >> 8;
    int r   = blockIdx.x & 255;
    int tid = threadIdx.x;
    int tb16 = r >> 4, lr = r & 15;
    int kk = tid >> 5, lg = (tid >> 3) & 3, j = tid & 7;
    size_t off = (((size_t)tb16*8 + kk) << 9) + (lr + 16*lg)*8 + j;
    if (seg == 6) {
        WoF[off] = f2bf(Wout[r*256 + tid]);                 // Wout[o][e]
    } else {
        const float* Wsrc = seg==0?Wtq: seg==1?Wtk: seg==2?Wtv: seg==3?Wvq: seg==4?Wvk: Wvv;
        Wf[((size_t)seg << 16) + off] = f2bf(Wsrc[tid*256 + r]);
    }
}

// ---------------- QKV projection via MFMA — fragment-tiled W loads ----------------
__global__ __launch_bounds__(256, 2) void k_qkv(const float* __restrict__ src,
    const short* __restrict__ WFq, const short* __restrict__ WFk, const short* __restrict__ WFv,
    short* __restrict__ Qb, short* __restrict__ Kf, short* __restrict__ Vf, int is_txt)
{
    __shared__ __align__(16) short xb[3][16][256];   // 24 KB
    __shared__ float invf[128];
    __shared__ float lbs[128];
    int tid = threadIdx.x;
    int r0 = blockIdx.x * 16;
    int b, srow0;
    if (is_txt) { b = r0 >> 5;  srow0 = r0 & 31; }
    else        { b = r0 >> 10; srow0 = TXT_ + (r0 & 1023); }
    int t16 = srow0 >> 4;

    if (tid < 128) {
        float fk = (float)tid;
        invf[tid] = exp2f(-fk*(1.f/128.f)*LOG2_10000f);
        lbs[tid]  = log2f((2.f*fk + 102.4f) * (1.f/358.4f));
    }
    __syncthreads();

    #pragma unroll
    for (int it = 0; it < 8; ++it) {
        int task = it*256 + tid;
        int k  = task >> 4;
        int rr = task & 15;
        int srow = srow0 + rr;
        float2 x01 = ((const float2*)(src + ((size_t)b*S_ + srow)*DM_))[k];
        float a0, a1, c0, c1;
        if (is_txt) {
            float xe  = (float)(srow + 1) * (TWO_PIf/(32.f + 1e-6f));
            float arg = xe * invf[k];
            float sn = __sinf(arg), cs = __cosf(arg);
            a0 = x01.x + sn; a1 = x01.y + cs;
            c0 = a0; c1 = a1;
        } else {
            int l = srow - TXT_;
            float arg = (float)l * invf[k];
            float sn = __sinf(arg), cs = __cosf(arg);
            float scale = exp2f((float)l*(1.f/512.f)*lbs[k]);
            float rsc = 1.f/scale;
            float y0 = x01.x*cs - x01.y*sn;
            float y1 = x01.y*cs + x01.x*sn;
            a0 = y0*scale; a1 = y1*scale;
            c0 = y0*rsc;   c1 = y1*rsc;
        }
        int col = (2*k) ^ ((rr&7)<<3);
        *(short2*)&xb[0][rr][col] = make_short2(f2bf(a0), f2bf(a1));
        *(short2*)&xb[1][rr][col] = make_short2(f2bf(c0), f2bf(c1));
        *(short2*)&xb[2][rr][col] = make_short2(f2bf(x01.x), f2bf(x01.y));
    }
    __syncthreads();

    int lane = tid & 63;
    int w    = tid >> 6;
    int lr   = lane & 15;
    int lg   = lane >> 4;
    int swzl = (lr & 7) << 3;

    const short* WFs[3] = {WFq, WFk, WFv};
    #pragma unroll
    for (int m = 0; m < 3; ++m) {
        bf16x8 xf[8];
        #pragma unroll
        for (int kk = 0; kk < 8; ++kk)
            xf[kk] = *(const bf16x8*)&xb[m][lr][(kk*32 + lg*8) ^ swzl];
        #pragma unroll
        for (int ct = 0; ct < 4; ++ct) {
            int tb16 = w + ct*4;
            int tb   = tb16 * 16;
            const short* Wp = WFs[m] + (((size_t)tb16*8) << 9) + lane*8;
            f32x4 acc = {0.f,0.f,0.f,0.f};
            if (m < 2) {
                #pragma unroll
                for (int kk = 0; kk < 8; ++kk) {
                    bf16x8 wf = *(const bf16x8*)(Wp + (kk << 9));
                    acc = __builtin_amdgcn_mfma_f32_16x16x32_bf16(wf, xf[kk], acc, 0, 0, 0);
                }
                int h  = tb >> 5;
                int d0 = (tb & 31) + lg*4;
                short4 s4;
                if (m == 0) {
                    s4.x=f2bf(acc[0]*RSQRT_DKf); s4.y=f2bf(acc[1]*RSQRT_DKf);
                    s4.z=f2bf(acc[2]*RSQRT_DKf); s4.w=f2bf(acc[3]*RSQRT_DKf);
                    size_t off = ((size_t)(b*H_+h)*S_ + srow0+lr)*DK_ + d0;
                    *(short4*)&Qb[off] = s4;
                } else {
                    s4.x=f2bf(acc[0]); s4.y=f2bf(acc[1]);
                    s4.z=f2bf(acc[2]); s4.w=f2bf(acc[3]);
                    int lK = lr + 16*(d0 >> 3);
                    *(short4*)&Kf[((((size_t)(b*H_+h)*NKT_ + t16) << 9)) + lK*8 + (d0 & 7)] = s4;
                }
            } else {
                #pragma unroll
                for (int kk = 0; kk < 8; ++kk) {
                    bf16x8 wf = *(const bf16x8*)(Wp + (kk << 9));
                    acc = __builtin_amdgcn_mfma_f32_16x16x32_bf16(xf[kk], wf, acc, 0, 0, 0);
                }
                int o = tb + lr;
                int h = o >> 5;
                int dh = (tb >> 4) & 1;
                short4 s4;
                s4.x=f2bf(acc[0]); s4.y=f2bf(acc[1]);
                s4.z=f2bf(acc[2]); s4.w=f2bf(acc[3]);
                *(short4*)&Vf[((((size_t)(b*H_+h)*NKT_ + t16)) << 9) + lane*8 + dh*4] = s4;
            }
        }
    }
}

// ---------------- kernel A: denominators + ctx — 48 q-rows/wave ----------------
// Per 16-k tile: 1 K + 1 V + 3 M loads -> 3 MFMA32 + 12 exp + 6 mfma16.
#define CTX_TILE3(KF, M0V, M1V, M2V, VV)                                           \
    {                                                                              \
        f32x4 acc0 = {0.f,0.f,0.f,0.f};                                            \
        acc0 = __builtin_amdgcn_mfma_f32_16x16x32_bf16(KF, qf0, acc0, 0, 0, 0);    \
        f32x4 acc1 = {0.f,0.f,0.f,0.f};                                            \
        acc1 = __builtin_amdgcn_mfma_f32_16x16x32_bf16(KF, qf1, acc1, 0, 0, 0);    \
        f32x4 acc2 = {0.f,0.f,0.f,0.f};                                            \
        acc2 = __builtin_amdgcn_mfma_f32_16x16x32_bf16(KF, qf2, acc2, 0, 0, 0);    \
        float e0 = fexp2(acc0[0]*bf2f(M0V.x));                                     \
        float e1 = fexp2(acc0[1]*bf2f(M0V.y));                                     \
        float e2 = fexp2(acc0[2]*bf2f(M0V.z));                                     \
        float e3 = fexp2(acc0[3]*bf2f(M0V.w));                                     \
        rssum0 += (e0+e1) + (e2+e3);                                               \
        bf16x4 pb0 = pack_bf16x4(e0, e1, e2, e3);                                  \
        float f0 = fexp2(acc1[0]*bf2f(M1V.x));                                     \
        float f1 = fexp2(acc1[1]*bf2f(M1V.y));                                     \
        float f2 = fexp2(acc1[2]*bf2f(M1V.z));                                     \
        float f3 = fexp2(acc1[3]*bf2f(M1V.w));                                     \
        rssum1 += (f0+f1) + (f2+f3);                                               \
        bf16x4 pb1 = pack_bf16x4(f0, f1, f2, f3);                                  \
        float g0 = fexp2(acc2[0]*bf2f(M2V.x));                                     \
        float g1 = fexp2(acc2[1]*bf2f(M2V.y));                                     \
        float g2 = fexp2(acc2[2]*bf2f(M2V.z));                                     \
        float g3 = fexp2(acc2[3]*bf2f(M2V.w));                                     \
        rssum2 += (g0+g1) + (g2+g3);                                               \
        bf16x4 pb2 = pack_bf16x4(g0, g1, g2, g3);                                  \
        bf16x4 vlo; vlo[0]=VV[0]; vlo[1]=VV[1]; vlo[2]=VV[2]; vlo[3]=VV[3];        \
        bf16x4 vhi; vhi[0]=VV[4]; vhi[1]=VV[5]; vhi[2]=VV[6]; vhi[3]=VV[7];        \
        pv00 = mfma16(pb0, vlo, pv00);                                             \
        pv01 = mfma16(pb0, vhi, pv01);                                             \
        pv10 = mfma16(pb1, vlo, pv10);                                             \
        pv11 = mfma16(pb1, vhi, pv11);                                             \
        pv20 = mfma16(pb2, vlo, pv20);                                             \
        pv21 = mfma16(pb2, vhi, pv21);                                             \
    }

__global__ __launch_bounds__(256, 3) void k_ctx(const short* __restrict__ Qb,
    const short* __restrict__ Kf, const short* __restrict__ Vf,
    const short* __restrict__ maskf, short* __restrict__ ctxf, float* __restrict__ denomG)
{
    int tid  = threadIdx.x;
    int lane = tid & 63;
    int w    = tid >> 6;          // wave 0..3
    int b    = blockIdx.x & 15;   // b-inner: XCD pinning (b%8)
    int qh   = blockIdx.x >> 4;   // 0..43
    int qt48 = qh >> 1;           // 0..21
    int head = (qh & 1)*4 + w;
    int q0   = qt48 * 48;
    int lr   = lane & 15;
    int lg   = lane >> 4;

    const int bh = b*H_ + head;
    bf16x8 qf0 = *(const bf16x8*)(Qb + ((size_t)bh*S_ + q0      + lr)*DK_ + lg*8);
    bf16x8 qf1 = *(const bf16x8*)(Qb + ((size_t)bh*S_ + q0 + 16 + lr)*DK_ + lg*8);
    bf16x8 qf2 = *(const bf16x8*)(Qb + ((size_t)bh*S_ + q0 + 32 + lr)*DK_ + lg*8);
    const short* Kp  = Kf + (((size_t)bh*NKT_) << 9) + lane*8;
    const short* Vp  = Vf + (((size_t)bh*NKT_) << 9) + lane*8;
    const short* Mp0 = maskf + (((size_t)(qt48*3    )*NKT_) << 8) + lane*4;
    const short* Mp1 = maskf + (((size_t)(qt48*3 + 1)*NKT_) << 8) + lane*4;
    const short* Mp2 = maskf + (((size_t)(qt48*3 + 2)*NKT_) << 8) + lane*4;

    float rssum0 = 0.f, rssum1 = 0.f, rssum2 = 0.f;
    f32x4 pv00 = {0.f,0.f,0.f,0.f}, pv01 = {0.f,0.f,0.f,0.f};
    f32x4 pv10 = {0.f,0.f,0.f,0.f}, pv11 = {0.f,0.f,0.f,0.f};
    f32x4 pv20 = {0.f,0.f,0.f,0.f}, pv21 = {0.f,0.f,0.f,0.f};

    for (int g = 0; g < 33; ++g) {
        int tb = g * 2;
        bf16x8 K[2], VV[2]; ushort4 M0[2], M1[2], M2[2];
        #pragma unroll
        for (int c = 0; c < 2; ++c) {
            int t = tb + c;
            K[c]  = *(const bf16x8*)(Kp + (unsigned)t*512);
            VV[c] = *(const bf16x8*)(Vp + (unsigned)t*512);
            M0[c] = *(const ushort4*)(Mp0 + (unsigned)t*256);
            M1[c] = *(const ushort4*)(Mp1 + (unsigned)t*256);
            M2[c] = *(const ushort4*)(Mp2 + (unsigned)t*256);
        }
        #pragma unroll
        for (int c = 0; c < 2; ++c) {
            CTX_TILE3(K[c], M0[c], M1[c], M2[c], VV[c])
        }
    }

    rssum0 += __shfl_xor(rssum0, 16, 64);
    rssum0 += __shfl_xor(rssum0, 32, 64);
    rssum1 += __shfl_xor(rssum1, 16, 64);
    rssum1 += __shfl_xor(rssum1, 32, 64);
    rssum2 += __shfl_xor(rssum2, 16, 64);
    rssum2 += __shfl_xor(rssum2, 32, 64);
    float rd0 = 1.f / rssum0;
    float rd1 = 1.f / rssum1;
    float rd2 = 1.f / rssum2;
    if (lane < 16) {
        denomG[(size_t)bh*S_ + q0      + lane] = rd0;
        denomG[(size_t)bh*S_ + q0 + 16 + lane] = rd1;
        denomG[(size_t)bh*S_ + q0 + 32 + lane] = rd2;
    }

    // ctxf fragment store
    size_t baseA = ((((size_t)b*NQT_ + qt48*3    )*8 + head) << 9);
    size_t baseB = ((((size_t)b*NQT_ + qt48*3 + 1)*8 + head) << 9);
    size_t baseC = ((((size_t)b*NQT_ + qt48*3 + 2)*8 + head) << 9);
    int j   = lr & 7;
    int lgl = lr >> 3;
    #pragma unroll
    for (int r = 0; r < 4; ++r) {
        float rdq0 = __shfl(rd0, 4*lg + r, 64);
        float rdq1 = __shfl(rd1, 4*lg + r, 64);
        float rdq2 = __shfl(rd2, 4*lg + r, 64);
        int qm = 4*lg + r;
        ctxf[baseA + (qm + 16*lgl    )*8 + j] = f2bf(pv00[r] * rdq0);
        ctxf[baseA + (qm + 16*(2+lgl))*8 + j] = f2bf(pv01[r] * rdq0);
        ctxf[baseB + (qm + 16*lgl    )*8 + j] = f2bf(pv10[r] * rdq1);
        ctxf[baseB + (qm + 16*(2+lgl))*8 + j] = f2bf(pv11[r] * rdq1);
        ctxf[baseC + (qm + 16*lgl    )*8 + j] = f2bf(pv20[r] * rdq2);
        ctxf[baseC + (qm + 16*(2+lgl))*8 + j] = f2bf(pv21[r] * rdq2);
    }
}

// ---------------- kernel B: att by score recompute — mfma(q,k), coalesced stores ----------------
// D[q=4lg+r][k=lr]; maskg fragment matches; att stores = 4 coalesced dword rows.
__global__ __launch_bounds__(256, 4) void k_att(const short* __restrict__ Qb,
    const short* __restrict__ Kf, const short* __restrict__ maskg,
    const float* __restrict__ denomG, float* __restrict__ att)
{
    int tid  = threadIdx.x;
    int lane = tid & 63;
    int w    = tid >> 6;
    int b    = blockIdx.x & 15;       // b-inner: XCD pinning
    int qt   = blockIdx.x >> 4;
    int q0   = qt * 16;
    int lr   = lane & 15;
    int lg   = lane >> 4;

    // denominators: float4 per head for q = q0+4lg..+3
    float4 rdv[8];
    #pragma unroll
    for (int h = 0; h < 8; ++h) {
        float4 v = *(const float4*)&denomG[(size_t)(b*H_+h)*S_ + q0 + 4*lg];
        rdv[h] = make_float4(v.x*0.125f, v.y*0.125f, v.z*0.125f, v.w*0.125f);
    }

    bf16x8 qf[8];
    #pragma unroll
    for (int h = 0; h < 8; ++h)
        qf[h] = *(const bf16x8*)(Qb + ((size_t)(b*H_+h)*S_ + q0+lr)*DK_ + lg*8);

    int nt = (w < 2) ? 17 : 16;
    for (int t = 0; t < nt; ++t) {
        int kt = t*4 + w;
        int k0 = kt*16;
        bf16x8 kf[8];
        #pragma unroll
        for (int h = 0; h < 8; ++h)
            kf[h] = *(const bf16x8*)(Kf + (((size_t)(b*H_+h)*NKT_ + kt) << 9) + lane*8);
        ushort4 mq = *(const ushort4*)(maskg + (((size_t)qt*NKT_ + kt) << 8) + lane*4);
        float m0 = bf2f(mq.x), m1 = bf2f(mq.y), m2 = bf2f(mq.z), m3 = bf2f(mq.w);
        f32x4 a = {0.f,0.f,0.f,0.f};
        #pragma unroll
        for (int h = 0; h < 8; ++h) {
            f32x4 s = {0.f,0.f,0.f,0.f};
            s = __builtin_amdgcn_mfma_f32_16x16x32_bf16(qf[h], kf[h], s, 0, 0, 0);
            a[0] = fmaf(fexp2(s[0]*m0), rdv[h].x, a[0]);
            a[1] = fmaf(fexp2(s[1]*m1), rdv[h].y, a[1]);
            a[2] = fmaf(fexp2(s[2]*m2), rdv[h].z, a[2]);
            a[3] = fmaf(fexp2(s[3]*m3), rdv[h].w, a[3]);
        }
        #pragma unroll
        for (int r = 0; r < 4; ++r)
            att[((size_t)b*S_ + q0 + 4*lg + r)*S_ + k0 + lr] = a[r];
    }
}

// ---------------- out projection via MFMA — fragment-tiled W and ctx loads ----------------
__global__ __launch_bounds__(256, 2) void k_outproj(const short* __restrict__ ctxf,
    const short* __restrict__ WoF, const float* __restrict__ bias, float* __restrict__ out)
{
    int tid  = threadIdx.x;
    int lane = tid & 63;
    int w    = tid >> 6;
    int lr   = lane & 15;
    int lg   = lane >> 4;
    int r0   = blockIdx.x * 16;       // global row tile index = blockIdx.x = b*66 + qt16

    bf16x8 cf[8];
    #pragma unroll
    for (int kk = 0; kk < 8; ++kk)
        cf[kk] = *(const bf16x8*)(ctxf + (((size_t)blockIdx.x*8 + kk) << 9) + lane*8);

    #pragma unroll
    for (int ct = 0; ct < 4; ++ct) {
        int tb16 = w + ct*4;
        int tb   = tb16 * 16;
        f32x4 acc = {0.f,0.f,0.f,0.f};
        #pragma unroll
        for (int kk = 0; kk < 8; ++kk) {
            bf16x8 wf = *(const bf16x8*)(WoF + (((size_t)tb16*8 + kk) << 9) + lane*8);
            acc = __builtin_amdgcn_mfma_f32_16x16x32_bf16(wf, cf[kk], acc, 0, 0, 0);
        }
        float4 b4 = *(const float4*)&bias[tb + lg*4];
        float4 o4 = make_float4(acc[0]+b4.x, acc[1]+b4.y, acc[2]+b4.z, acc[3]+b4.w);
        *(float4*)&out[(size_t)(r0+lr)*DM_ + tb + lg*4] = o4;
    }
}

extern "C" void kernel_launch(void* const* d_in, const int* in_sizes, int n_in,
                              void* d_out, int out_size, void* d_ws, size_t ws_size,
                              hipStream_t stream)
{
    (void)in_sizes; (void)n_in; (void)out_size; (void)ws_size;
    const float* src  = (const float*)d_in[0];
    const float* Wtq  = (const float*)d_in[1];
    const float* Wtk  = (const float*)d_in[2];
    const float* Wtv  = (const float*)d_in[3];
    const float* Wvq  = (const float*)d_in[4];
    const float* Wvk  = (const float*)d_in[5];
    const float* Wvv  = (const float*)d_in[6];
    const float* lvr  = (const float*)d_in[7];
    const float* Wout = (const float*)d_in[8];
    const float* bout = (const float*)d_in[9];
    const int*   rid  = (const int*)d_in[10];
    const int*   cid  = (const int*)d_in[11];

    const size_t QKV_SH = (size_t)B_*H_*S_*DK_;      // Qb shorts
    const size_t KF_SH  = (size_t)B_*H_*NKT_*512;    // Kf shorts
    const size_t VF_SH  = (size_t)B_*H_*NKT_*512;    // Vf shorts
    const size_t CTX_SH = (size_t)B_*S_*DM_;

    float* ws       = (float*)d_ws;
    float* partials = ws;                             // MASK_BLKS
    float* denomG   = partials + MASK_BLKS;           // B*H*S
    short* maskf    = (short*)(denomG + (size_t)B_*H_*S_);
    short* maskg    = maskf + SS_;
    short* Qb       = maskg + SS_;
    short* Kf       = Qb + QKV_SH;
    short* Vf       = Kf + KF_SH;
    short* ctxf     = Vf + VF_SH;
    short* Wf       = ctxf + CTX_SH;                  // 6*65536
    short* WoF      = Wf + 6*65536;

    float* out  = (float*)d_out;
    float* att  = out + (size_t)B_*S_*DM_;
    float* loss = att + (size_t)B_*S_*S_;

    k_mask<<<MASK_BLKS, 256, 0, stream>>>(lvr, rid, cid, maskf, maskg, partials);
    k_wprep<<<7*256, 256, 0, stream>>>(Wtq, Wtk, Wtv, Wvq, Wvk, Wvv, Wout, Wf, WoF);
    k_qkv<<<(B_*TXT_)/16, 256, 0, stream>>>(src, Wf, Wf+65536, Wf+2*65536,
                                            Qb, Kf, Vf, 1);
    k_qkv<<<(B_*VID_)/16, 256, 0, stream>>>(src, Wf+3*65536, Wf+4*65536, Wf+5*65536,
                                            Qb, Kf, Vf, 0);
    k_ctx<<<B_*NQ48_*2, 256, 0, stream>>>(Qb, Kf, Vf, maskf, ctxf, denomG);
    k_att<<<B_*NQT_, 256, 0, stream>>>(Qb, Kf, maskg, denomG, att);
    k_outproj<<<(B_*S_)/16, 256, 0, stream>>>(ctxf, WoF, bout, out);
    k_loss<<<1, 256, 0, stream>>>(partials, loss);
}

// Round 19
// 155.591 us; speedup vs baseline: 1.5519x; 1.0193x over previous
//
#include <hip/hip_runtime.h>
#include <math.h>

#define B_   16
#define S_   1056
#define DM_  256
#define H_   8
#define DK_  32
#define TXT_ 32
#define VID_ 1024
#define SS_  (S_*S_)          // 1115136
#define NQT_ 66               // q-tiles of 16 rows
#define NKT_ 66               // k-tiles of 16
#define NQ48_ 22              // q-tiles of 48 rows
#define NQ32_ 33              // q-tiles of 32 rows (k_att)
#define MASK_BLKS 1089        // (66*66*64)/256

#define LOG2_10000f 13.28771237954945f
#define LOG2_GAMMAf (-0.15200309344504995f)   // log2(0.9)
#define RSQRT_DKf   0.17677669529663687f      // 1/sqrt(32)
#define TWO_PIf     6.283185307179586f
#define LOG2Ef      1.4426950408889634f

typedef __attribute__((ext_vector_type(8))) short bf16x8;
typedef __attribute__((ext_vector_type(4))) short bf16x4;
typedef __attribute__((ext_vector_type(4))) float f32x4;

__device__ __forceinline__ short f2bf(float f){
    unsigned u = __float_as_uint(f);
    unsigned r = u + 0x7FFFu + ((u >> 16) & 1u);   // RNE
    return (short)(r >> 16);
}
__device__ __forceinline__ float bf2f(unsigned short s){
    return __uint_as_float(((unsigned)s) << 16);
}
__device__ __forceinline__ float fexp2(float x){
#if __has_builtin(__builtin_amdgcn_exp2f)
    return __builtin_amdgcn_exp2f(x);
#else
    return exp2f(x);
#endif
}
__device__ __forceinline__ bf16x4 pack_bf16x4(float e0, float e1, float e2, float e3){
    unsigned w0, w1;
    asm("v_cvt_pk_bf16_f32 %0, %1, %2" : "=v"(w0) : "v"(e0), "v"(e1));
    asm("v_cvt_pk_bf16_f32 %0, %1, %2" : "=v"(w1) : "v"(e2), "v"(e3));
    uint2 u = make_uint2(w0, w1);
    return *(bf16x4*)&u;
}

// K=16 bf16 MFMA: A-frag lane l holds A[row=l%16][k=4(l/16)+j] — matches the
// QK^T D-fragment, so P feeds PV in-lane.
__device__ __forceinline__ f32x4 mfma16(bf16x4 a, bf16x4 b, f32x4 c){
#if __has_builtin(__builtin_amdgcn_mfma_f32_16x16x16bf16_1k)
    return __builtin_amdgcn_mfma_f32_16x16x16bf16_1k(a, b, c, 0, 0, 0);
#else
    f32x4 d = c;
    asm("v_mfma_f32_16x16x16_bf16 %0, %1, %2, %0" : "+v"(d) : "v"(a), "v"(b));
    return d;
#endif
}

// ---------------- mask: maskf (q=lr frag, for k_ctx) + maskg (k=lr frag, for k_att) ----------------
__global__ __launch_bounds__(256) void k_mask(const float* __restrict__ lvr,
                       const int* __restrict__ row_idx, const int* __restrict__ col_idx,
                       short* __restrict__ maskf, short* __restrict__ maskg,
                       float* __restrict__ partials)
{
    int T  = blockIdx.x*256 + threadIdx.x;
    int l  = T & 63;
    int qk = T >> 6;                  // qt*66 + kt
    int qt = qk / 66;
    int kt = qk - qt*66;
    int i  = qt*16 + (l & 15);
    int j0 = kt*16 + 4*(l >> 4);
    size_t idx = (size_t)i*S_ + j0;
    int4 ri4 = *(const int4*)&row_idx[idx];
    int4 ci4 = *(const int4*)&col_idx[idx];
    int rr[4] = {ri4.x, ri4.y, ri4.z, ri4.w};
    int cc[4] = {ci4.x, ci4.y, ci4.z, ci4.w};
    float vrs = 0.f;
    short4 mq;
    short* mp = (short*)&mq;
    #pragma unroll
    for (int jj = 0; jj < 4; ++jj) {
        int j = j0 + jj;
        float vr, lm;
        if (i == j) { vr = 0.f; lm = 1.f; }
        else {
            float t = lvr[(size_t)rr[jj]*VID_ + cc[jj]];
            float sg = 1.f/(1.f + expf(-t));
            vr = sg; lm = sg;
        }
        float dmat = (i >= j) ? exp2f((float)(i-j)*LOG2_GAMMAf) : 0.f;
        mp[jj] = f2bf(dmat * lm * LOG2Ef);   // exp(s*m) = exp2(s*m')
        vrs += vr;
    }
    *(short4*)&maskf[(size_t)qk*256 + l*4] = mq;
    // maskg: lane' = (k&15) + 16*((q&15)>>2), slot r' = q&3
    {
        int lq = l & 15;
        int r2 = lq & 3;
        int baseq = (lq >> 2) << 4;
        #pragma unroll
        for (int jj = 0; jj < 4; ++jj) {
            int lanep = 4*(l >> 4) + jj + baseq;
            maskg[(size_t)qk*256 + lanep*4 + r2] = mp[jj];
        }
    }

    float s = vrs;
    #pragma unroll
    for (int m=1; m<64; m<<=1) s += __shfl_xor(s, m, 64);
    __shared__ float ws4[4];
    if ((threadIdx.x & 63) == 0) ws4[threadIdx.x>>6] = s;
    __syncthreads();
    if (threadIdx.x == 0) partials[blockIdx.x] = ws4[0]+ws4[1]+ws4[2]+ws4[3];
}

__global__ __launch_bounds__(256) void k_loss(const float* __restrict__ partials,
                                              float* __restrict__ out_loss)
{
    float s = 0.f;
    for (int i = threadIdx.x; i < MASK_BLKS; i += 256) s += partials[i];
    #pragma unroll
    for (int m=1; m<64; m<<=1) s += __shfl_xor(s, m, 64);
    __shared__ float ws4[4];
    if ((threadIdx.x & 63) == 0) ws4[threadIdx.x>>6] = s;
    __syncthreads();
    if (threadIdx.x == 0) out_loss[0] = (ws4[0]+ws4[1]+ws4[2]+ws4[3]) * (1.f/(float)SS_);
}

// ---------------- weight prep -> MFMA-fragment tiles ----------------
__global__ __launch_bounds__(256) void k_wprep(
    const float* __restrict__ Wtq, const float* __restrict__ Wtk, const float* __restrict__ Wtv,
    const float* __restrict__ Wvq, const float* __restrict__ Wvk, const float* __restrict__ Wvv,
    const float* __restrict__ Wout, short* __restrict__ Wf, short* __restrict__ WoF)
{
    int seg = blockIdx.x >> 8;
    int r   = blockIdx.x & 255;
    int tid = threadIdx.x;
    int tb16 = r >> 4, lr = r & 15;
    int kk = tid >> 5, lg = (tid >> 3) & 3, j = tid & 7;
    size_t off = (((size_t)tb16*8 + kk) << 9) + (lr + 16*lg)*8 + j;
    if (seg == 6) {
        WoF[off] = f2bf(Wout[r*256 + tid]);                 // Wout[o][e]
    } else {
        const float* Wsrc = seg==0?Wtq: seg==1?Wtk: seg==2?Wtv: seg==3?Wvq: seg==4?Wvk: Wvv;
        Wf[((size_t)seg << 16) + off] = f2bf(Wsrc[tid*256 + r]);
    }
}

// ---------------- QKV projection via MFMA — fragment-tiled W loads ----------------
__global__ __launch_bounds__(256, 2) void k_qkv(const float* __restrict__ src,
    const short* __restrict__ WFq, const short* __restrict__ WFk, const short* __restrict__ WFv,
    short* __restrict__ Qb, short* __restrict__ Kf, short* __restrict__ Vf, int is_txt)
{
    __shared__ __align__(16) short xb[3][16][256];   // 24 KB
    __shared__ float invf[128];
    __shared__ float lbs[128];
    int tid = threadIdx.x;
    int r0 = blockIdx.x * 16;
    int b, srow0;
    if (is_txt) { b = r0 >> 5;  srow0 = r0 & 31; }
    else        { b = r0 >> 10; srow0 = TXT_ + (r0 & 1023); }
    int t16 = srow0 >> 4;

    if (tid < 128) {
        float fk = (float)tid;
        invf[tid] = exp2f(-fk*(1.f/128.f)*LOG2_10000f);
        lbs[tid]  = log2f((2.f*fk + 102.4f) * (1.f/358.4f));
    }
    __syncthreads();

    #pragma unroll
    for (int it = 0; it < 8; ++it) {
        int task = it*256 + tid;
        int k  = task >> 4;
        int rr = task & 15;
        int srow = srow0 + rr;
        float2 x01 = ((const float2*)(src + ((size_t)b*S_ + srow)*DM_))[k];
        float a0, a1, c0, c1;
        if (is_txt) {
            float xe  = (float)(srow + 1) * (TWO_PIf/(32.f + 1e-6f));
            float arg = xe * invf[k];
            float sn = __sinf(arg), cs = __cosf(arg);
            a0 = x01.x + sn; a1 = x01.y + cs;
            c0 = a0; c1 = a1;
        } else {
            int l = srow - TXT_;
            float arg = (float)l * invf[k];
            float sn = __sinf(arg), cs = __cosf(arg);
            float scale = exp2f((float)l*(1.f/512.f)*lbs[k]);
            float rsc = 1.f/scale;
            float y0 = x01.x*cs - x01.y*sn;
            float y1 = x01.y*cs + x01.x*sn;
            a0 = y0*scale; a1 = y1*scale;
            c0 = y0*rsc;   c1 = y1*rsc;
        }
        int col = (2*k) ^ ((rr&7)<<3);
        *(short2*)&xb[0][rr][col] = make_short2(f2bf(a0), f2bf(a1));
        *(short2*)&xb[1][rr][col] = make_short2(f2bf(c0), f2bf(c1));
        *(short2*)&xb[2][rr][col] = make_short2(f2bf(x01.x), f2bf(x01.y));
    }
    __syncthreads();

    int lane = tid & 63;
    int w    = tid >> 6;
    int lr   = lane & 15;
    int lg   = lane >> 4;
    int swzl = (lr & 7) << 3;

    const short* WFs[3] = {WFq, WFk, WFv};
    #pragma unroll
    for (int m = 0; m < 3; ++m) {
        bf16x8 xf[8];
        #pragma unroll
        for (int kk = 0; kk < 8; ++kk)
            xf[kk] = *(const bf16x8*)&xb[m][lr][(kk*32 + lg*8) ^ swzl];
        #pragma unroll
        for (int ct = 0; ct < 4; ++ct) {
            int tb16 = w + ct*4;
            int tb   = tb16 * 16;
            const short* Wp = WFs[m] + (((size_t)tb16*8) << 9) + lane*8;
            f32x4 acc = {0.f,0.f,0.f,0.f};
            if (m < 2) {
                #pragma unroll
                for (int kk = 0; kk < 8; ++kk) {
                    bf16x8 wf = *(const bf16x8*)(Wp + (kk << 9));
                    acc = __builtin_amdgcn_mfma_f32_16x16x32_bf16(wf, xf[kk], acc, 0, 0, 0);
                }
                int h  = tb >> 5;
                int d0 = (tb & 31) + lg*4;
                short4 s4;
                if (m == 0) {
                    s4.x=f2bf(acc[0]*RSQRT_DKf); s4.y=f2bf(acc[1]*RSQRT_DKf);
                    s4.z=f2bf(acc[2]*RSQRT_DKf); s4.w=f2bf(acc[3]*RSQRT_DKf);
                    size_t off = ((size_t)(b*H_+h)*S_ + srow0+lr)*DK_ + d0;
                    *(short4*)&Qb[off] = s4;
                } else {
                    s4.x=f2bf(acc[0]); s4.y=f2bf(acc[1]);
                    s4.z=f2bf(acc[2]); s4.w=f2bf(acc[3]);
                    int lK = lr + 16*(d0 >> 3);
                    *(short4*)&Kf[((((size_t)(b*H_+h)*NKT_ + t16) << 9)) + lK*8 + (d0 & 7)] = s4;
                }
            } else {
                #pragma unroll
                for (int kk = 0; kk < 8; ++kk) {
                    bf16x8 wf = *(const bf16x8*)(Wp + (kk << 9));
                    acc = __builtin_amdgcn_mfma_f32_16x16x32_bf16(xf[kk], wf, acc, 0, 0, 0);
                }
                int o = tb + lr;
                int h = o >> 5;
                int dh = (tb >> 4) & 1;
                short4 s4;
                s4.x=f2bf(acc[0]); s4.y=f2bf(acc[1]);
                s4.z=f2bf(acc[2]); s4.w=f2bf(acc[3]);
                *(short4*)&Vf[((((size_t)(b*H_+h)*NKT_ + t16)) << 9) + lane*8 + dh*4] = s4;
            }
        }
    }
}

// ---------------- kernel A: denominators + ctx — 48 q-rows/wave ----------------
#define CTX_TILE3(KF, M0V, M1V, M2V, VV)                                           \
    {                                                                              \
        f32x4 acc0 = {0.f,0.f,0.f,0.f};                                            \
        acc0 = __builtin_amdgcn_mfma_f32_16x16x32_bf16(KF, qf0, acc0, 0, 0, 0);    \
        f32x4 acc1 = {0.f,0.f,0.f,0.f};                                            \
        acc1 = __builtin_amdgcn_mfma_f32_16x16x32_bf16(KF, qf1, acc1, 0, 0, 0);    \
        f32x4 acc2 = {0.f,0.f,0.f,0.f};                                            \
        acc2 = __builtin_amdgcn_mfma_f32_16x16x32_bf16(KF, qf2, acc2, 0, 0, 0);    \
        float e0 = fexp2(acc0[0]*bf2f(M0V.x));                                     \
        float e1 = fexp2(acc0[1]*bf2f(M0V.y));                                     \
        float e2 = fexp2(acc0[2]*bf2f(M0V.z));                                     \
        float e3 = fexp2(acc0[3]*bf2f(M0V.w));                                     \
        rssum0 += (e0+e1) + (e2+e3);                                               \
        bf16x4 pb0 = pack_bf16x4(e0, e1, e2, e3);                                  \
        float f0 = fexp2(acc1[0]*bf2f(M1V.x));                                     \
        float f1 = fexp2(acc1[1]*bf2f(M1V.y));                                     \
        float f2 = fexp2(acc1[2]*bf2f(M1V.z));                                     \
        float f3 = fexp2(acc1[3]*bf2f(M1V.w));                                     \
        rssum1 += (f0+f1) + (f2+f3);                                               \
        bf16x4 pb1 = pack_bf16x4(f0, f1, f2, f3);                                  \
        float g0 = fexp2(acc2[0]*bf2f(M2V.x));                                     \
        float g1 = fexp2(acc2[1]*bf2f(M2V.y));                                     \
        float g2 = fexp2(acc2[2]*bf2f(M2V.z));                                     \
        float g3 = fexp2(acc2[3]*bf2f(M2V.w));                                     \
        rssum2 += (g0+g1) + (g2+g3);                                               \
        bf16x4 pb2 = pack_bf16x4(g0, g1, g2, g3);                                  \
        bf16x4 vlo; vlo[0]=VV[0]; vlo[1]=VV[1]; vlo[2]=VV[2]; vlo[3]=VV[3];        \
        bf16x4 vhi; vhi[0]=VV[4]; vhi[1]=VV[5]; vhi[2]=VV[6]; vhi[3]=VV[7];        \
        pv00 = mfma16(pb0, vlo, pv00);                                             \
        pv01 = mfma16(pb0, vhi, pv01);                                             \
        pv10 = mfma16(pb1, vlo, pv10);                                             \
        pv11 = mfma16(pb1, vhi, pv11);                                             \
        pv20 = mfma16(pb2, vlo, pv20);                                             \
        pv21 = mfma16(pb2, vhi, pv21);                                             \
    }

__global__ __launch_bounds__(256, 3) void k_ctx(const short* __restrict__ Qb,
    const short* __restrict__ Kf, const short* __restrict__ Vf,
    const short* __restrict__ maskf, short* __restrict__ ctxf, float* __restrict__ denomG)
{
    int tid  = threadIdx.x;
    int lane = tid & 63;
    int w    = tid >> 6;          // wave 0..3
    int b    = blockIdx.x & 15;   // b-inner: XCD pinning (b%8)
    int qh   = blockIdx.x >> 4;   // 0..43
    int qt48 = qh >> 1;           // 0..21
    int head = (qh & 1)*4 + w;
    int q0   = qt48 * 48;
    int lr   = lane & 15;
    int lg   = lane >> 4;

    const int bh = b*H_ + head;
    bf16x8 qf0 = *(const bf16x8*)(Qb + ((size_t)bh*S_ + q0      + lr)*DK_ + lg*8);
    bf16x8 qf1 = *(const bf16x8*)(Qb + ((size_t)bh*S_ + q0 + 16 + lr)*DK_ + lg*8);
    bf16x8 qf2 = *(const bf16x8*)(Qb + ((size_t)bh*S_ + q0 + 32 + lr)*DK_ + lg*8);
    const short* Kp  = Kf + (((size_t)bh*NKT_) << 9) + lane*8;
    const short* Vp  = Vf + (((size_t)bh*NKT_) << 9) + lane*8;
    const short* Mp0 = maskf + (((size_t)(qt48*3    )*NKT_) << 8) + lane*4;
    const short* Mp1 = maskf + (((size_t)(qt48*3 + 1)*NKT_) << 8) + lane*4;
    const short* Mp2 = maskf + (((size_t)(qt48*3 + 2)*NKT_) << 8) + lane*4;

    float rssum0 = 0.f, rssum1 = 0.f, rssum2 = 0.f;
    f32x4 pv00 = {0.f,0.f,0.f,0.f}, pv01 = {0.f,0.f,0.f,0.f};
    f32x4 pv10 = {0.f,0.f,0.f,0.f}, pv11 = {0.f,0.f,0.f,0.f};
    f32x4 pv20 = {0.f,0.f,0.f,0.f}, pv21 = {0.f,0.f,0.f,0.f};

    for (int g = 0; g < 33; ++g) {
        int tb = g * 2;
        bf16x8 K[2], VV[2]; ushort4 M0[2], M1[2], M2[2];
        #pragma unroll
        for (int c = 0; c < 2; ++c) {
            int t = tb + c;
            K[c]  = *(const bf16x8*)(Kp + (unsigned)t*512);
            VV[c] = *(const bf16x8*)(Vp + (unsigned)t*512);
            M0[c] = *(const ushort4*)(Mp0 + (unsigned)t*256);
            M1[c] = *(const ushort4*)(Mp1 + (unsigned)t*256);
            M2[c] = *(const ushort4*)(Mp2 + (unsigned)t*256);
        }
        #pragma unroll
        for (int c = 0; c < 2; ++c) {
            CTX_TILE3(K[c], M0[c], M1[c], M2[c], VV[c])
        }
    }

    rssum0 += __shfl_xor(rssum0, 16, 64);
    rssum0 += __shfl_xor(rssum0, 32, 64);
    rssum1 += __shfl_xor(rssum1, 16, 64);
    rssum1 += __shfl_xor(rssum1, 32, 64);
    rssum2 += __shfl_xor(rssum2, 16, 64);
    rssum2 += __shfl_xor(rssum2, 32, 64);
    float rd0 = 1.f / rssum0;
    float rd1 = 1.f / rssum1;
    float rd2 = 1.f / rssum2;
    if (lane < 16) {
        denomG[(size_t)bh*S_ + q0      + lane] = rd0;
        denomG[(size_t)bh*S_ + q0 + 16 + lane] = rd1;
        denomG[(size_t)bh*S_ + q0 + 32 + lane] = rd2;
    }

    size_t baseA = ((((size_t)b*NQT_ + qt48*3    )*8 + head) << 9);
    size_t baseB = ((((size_t)b*NQT_ + qt48*3 + 1)*8 + head) << 9);
    size_t baseC = ((((size_t)b*NQT_ + qt48*3 + 2)*8 + head) << 9);
    int j   = lr & 7;
    int lgl = lr >> 3;
    #pragma unroll
    for (int r = 0; r < 4; ++r) {
        float rdq0 = __shfl(rd0, 4*lg + r, 64);
        float rdq1 = __shfl(rd1, 4*lg + r, 64);
        float rdq2 = __shfl(rd2, 4*lg + r, 64);
        int qm = 4*lg + r;
        ctxf[baseA + (qm + 16*lgl    )*8 + j] = f2bf(pv00[r] * rdq0);
        ctxf[baseA + (qm + 16*(2+lgl))*8 + j] = f2bf(pv01[r] * rdq0);
        ctxf[baseB + (qm + 16*lgl    )*8 + j] = f2bf(pv10[r] * rdq1);
        ctxf[baseB + (qm + 16*(2+lgl))*8 + j] = f2bf(pv11[r] * rdq1);
        ctxf[baseC + (qm + 16*lgl    )*8 + j] = f2bf(pv20[r] * rdq2);
        ctxf[baseC + (qm + 16*(2+lgl))*8 + j] = f2bf(pv21[r] * rdq2);
    }
}

// ---------------- kernel B: att — 32 q-rows/block, kf reused across 2 q-tiles ----------------
__global__ __launch_bounds__(256, 2) void k_att(const short* __restrict__ Qb,
    const short* __restrict__ Kf, const short* __restrict__ maskg,
    const float* __restrict__ denomG, float* __restrict__ att)
{
    int tid  = threadIdx.x;
    int lane = tid & 63;
    int w    = tid >> 6;
    int b    = blockIdx.x & 15;       // b-inner: XCD pinning
    int qp   = blockIdx.x >> 4;       // 0..32
    int q0   = qp * 32;
    int qt0  = qp*2, qt1 = qp*2 + 1;  // 16-row tile indices
    int lr   = lane & 15;
    int lg   = lane >> 4;

    float4 rdv0[8], rdv1[8];
    #pragma unroll
    for (int h = 0; h < 8; ++h) {
        float4 v0 = *(const float4*)&denomG[(size_t)(b*H_+h)*S_ + q0 + 4*lg];
        float4 v1 = *(const float4*)&denomG[(size_t)(b*H_+h)*S_ + q0 + 16 + 4*lg];
        rdv0[h] = make_float4(v0.x*0.125f, v0.y*0.125f, v0.z*0.125f, v0.w*0.125f);
        rdv1[h] = make_float4(v1.x*0.125f, v1.y*0.125f, v1.z*0.125f, v1.w*0.125f);
    }

    bf16x8 qf0[8], qf1[8];
    #pragma unroll
    for (int h = 0; h < 8; ++h) {
        qf0[h] = *(const bf16x8*)(Qb + ((size_t)(b*H_+h)*S_ + q0      + lr)*DK_ + lg*8);
        qf1[h] = *(const bf16x8*)(Qb + ((size_t)(b*H_+h)*S_ + q0 + 16 + lr)*DK_ + lg*8);
    }

    int nt = (w < 2) ? 17 : 16;
    for (int t = 0; t < nt; ++t) {
        int kt = t*4 + w;
        int k0 = kt*16;
        bf16x8 kf[8];
        #pragma unroll
        for (int h = 0; h < 8; ++h)
            kf[h] = *(const bf16x8*)(Kf + (((size_t)(b*H_+h)*NKT_ + kt) << 9) + lane*8);
        ushort4 mq0 = *(const ushort4*)(maskg + (((size_t)qt0*NKT_ + kt) << 8) + lane*4);
        ushort4 mq1 = *(const ushort4*)(maskg + (((size_t)qt1*NKT_ + kt) << 8) + lane*4);
        float m00 = bf2f(mq0.x), m01 = bf2f(mq0.y), m02 = bf2f(mq0.z), m03 = bf2f(mq0.w);
        float m10 = bf2f(mq1.x), m11 = bf2f(mq1.y), m12 = bf2f(mq1.z), m13 = bf2f(mq1.w);
        f32x4 a0 = {0.f,0.f,0.f,0.f};
        f32x4 a1 = {0.f,0.f,0.f,0.f};
        #pragma unroll
        for (int h = 0; h < 8; ++h) {
            f32x4 s0 = {0.f,0.f,0.f,0.f};
            s0 = __builtin_amdgcn_mfma_f32_16x16x32_bf16(qf0[h], kf[h], s0, 0, 0, 0);
            a0[0] = fmaf(fexp2(s0[0]*m00), rdv0[h].x, a0[0]);
            a0[1] = fmaf(fexp2(s0[1]*m01), rdv0[h].y, a0[1]);
            a0[2] = fmaf(fexp2(s0[2]*m02), rdv0[h].z, a0[2]);
            a0[3] = fmaf(fexp2(s0[3]*m03), rdv0[h].w, a0[3]);
            f32x4 s1 = {0.f,0.f,0.f,0.f};
            s1 = __builtin_amdgcn_mfma_f32_16x16x32_bf16(qf1[h], kf[h], s1, 0, 0, 0);
            a1[0] = fmaf(fexp2(s1[0]*m10), rdv1[h].x, a1[0]);
            a1[1] = fmaf(fexp2(s1[1]*m11), rdv1[h].y, a1[1]);
            a1[2] = fmaf(fexp2(s1[2]*m12), rdv1[h].z, a1[2]);
            a1[3] = fmaf(fexp2(s1[3]*m13), rdv1[h].w, a1[3]);
        }
        #pragma unroll
        for (int r = 0; r < 4; ++r) {
            att[((size_t)b*S_ + q0      + 4*lg + r)*S_ + k0 + lr] = a0[r];
            att[((size_t)b*S_ + q0 + 16 + 4*lg + r)*S_ + k0 + lr] = a1[r];
        }
    }
}

// ---------------- out projection via MFMA — fragment-tiled W and ctx loads ----------------
__global__ __launch_bounds__(256, 2) void k_outproj(const short* __restrict__ ctxf,
    const short* __restrict__ WoF, const float* __restrict__ bias, float* __restrict__ out)
{
    int tid  = threadIdx.x;
    int lane = tid & 63;
    int w    = tid >> 6;
    int lr   = lane & 15;
    int lg   = lane >> 4;
    int r0   = blockIdx.x * 16;       // global row tile index = blockIdx.x = b*66 + qt16

    bf16x8 cf[8];
    #pragma unroll
    for (int kk = 0; kk < 8; ++kk)
        cf[kk] = *(const bf16x8*)(ctxf + (((size_t)blockIdx.x*8 + kk) << 9) + lane*8);

    #pragma unroll
    for (int ct = 0; ct < 4; ++ct) {
        int tb16 = w + ct*4;
        int tb   = tb16 * 16;
        f32x4 acc = {0.f,0.f,0.f,0.f};
        #pragma unroll
        for (int kk = 0; kk < 8; ++kk) {
            bf16x8 wf = *(const bf16x8*)(WoF + (((size_t)tb16*8 + kk) << 9) + lane*8);
            acc = __builtin_amdgcn_mfma_f32_16x16x32_bf16(wf, cf[kk], acc, 0, 0, 0);
        }
        float4 b4 = *(const float4*)&bias[tb + lg*4];
        float4 o4 = make_float4(acc[0]+b4.x, acc[1]+b4.y, acc[2]+b4.z, acc[3]+b4.w);
        *(float4*)&out[(size_t)(r0+lr)*DM_ + tb + lg*4] = o4;
    }
}

extern "C" void kernel_launch(void* const* d_in, const int* in_sizes, int n_in,
                              void* d_out, int out_size, void* d_ws, size_t ws_size,
                              hipStream_t stream)
{
    (void)in_sizes; (void)n_in; (void)out_size; (void)ws_size;
    const float* src  = (const float*)d_in[0];
    const float* Wtq  = (const float*)d_in[1];
    const float* Wtk  = (const float*)d_in[2];
    const float* Wtv  = (const float*)d_in[3];
    const float* Wvq  = (const float*)d_in[4];
    const float* Wvk  = (const float*)d_in[5];
    const float* Wvv  = (const float*)d_in[6];
    const float* lvr  = (const float*)d_in[7];
    const float* Wout = (const float*)d_in[8];
    const float* bout = (const float*)d_in[9];
    const int*   rid  = (const int*)d_in[10];
    const int*   cid  = (const int*)d_in[11];

    const size_t QKV_SH = (size_t)B_*H_*S_*DK_;      // Qb shorts
    const size_t KF_SH  = (size_t)B_*H_*NKT_*512;    // Kf shorts
    const size_t VF_SH  = (size_t)B_*H_*NKT_*512;    // Vf shorts
    const size_t CTX_SH = (size_t)B_*S_*DM_;

    float* ws       = (float*)d_ws;
    float* partials = ws;                             // MASK_BLKS
    float* denomG   = partials + MASK_BLKS;           // B*H*S
    short* maskf    = (short*)(denomG + (size_t)B_*H_*S_);
    short* maskg    = maskf + SS_;
    short* Qb       = maskg + SS_;
    short* Kf       = Qb + QKV_SH;
    short* Vf       = Kf + KF_SH;
    short* ctxf     = Vf + VF_SH;
    short* Wf       = ctxf + CTX_SH;                  // 6*65536
    short* WoF      = Wf + 6*65536;

    float* out  = (float*)d_out;
    float* att  = out + (size_t)B_*S_*DM_;
    float* loss = att + (size_t)B_*S_*S_;

    k_mask<<<MASK_BLKS, 256, 0, stream>>>(lvr, rid, cid, maskf, maskg, partials);
    k_wprep<<<7*256, 256, 0, stream>>>(Wtq, Wtk, Wtv, Wvq, Wvk, Wvv, Wout, Wf, WoF);
    k_qkv<<<(B_*TXT_)/16, 256, 0, stream>>>(src, Wf, Wf+65536, Wf+2*65536,
                                            Qb, Kf, Vf, 1);
    k_qkv<<<(B_*VID_)/16, 256, 0, stream>>>(src, Wf+3*65536, Wf+4*65536, Wf+5*65536,
                                            Qb, Kf, Vf, 0);
    k_ctx<<<B_*NQ48_*2, 256, 0, stream>>>(Qb, Kf, Vf, maskf, ctxf, denomG);
    k_att<<<B_*NQ32_, 256, 0, stream>>>(Qb, Kf, maskg, denomG, att);
    k_outproj<<<(B_*S_)/16, 256, 0, stream>>>(ctxf, WoF, bout, out);
    k_loss<<<1, 256, 0, stream>>>(partials, loss);
}